// Round 1
// baseline (1548.371 us; speedup 1.0000x reference)
//
#include <hip/hip_runtime.h>
#include <hip/hip_bf16.h>

#define N_NODES 100000
#define N_EDGES 1600000
#define HID 64
#define NODE_DIM 128

typedef __attribute__((ext_vector_type(8))) short bf16x8;
typedef __attribute__((ext_vector_type(4))) float f32x4;

__device__ __forceinline__ unsigned short f2bf(float f) {
  __hip_bfloat16 h = __float2bfloat16(f);
  return *reinterpret_cast<unsigned short*>(&h);
}

// ---- encoder: h = relu(x @ W + b), x [N,128], W [128,64], wave per row ----
__global__ void k_encode(const float* __restrict__ x, const float* __restrict__ w,
                         const float* __restrict__ b, float* __restrict__ h) {
  __shared__ float wl[NODE_DIM * HID];
  for (int i = threadIdx.x; i < NODE_DIM * HID; i += blockDim.x) wl[i] = w[i];
  __syncthreads();
  const int lane = threadIdx.x & 63;
  const int wid = threadIdx.x >> 6;
  const int wpb = blockDim.x >> 6;
  const int nw = gridDim.x * wpb;
  for (int row = blockIdx.x * wpb + wid; row < N_NODES; row += nw) {
    float x0 = x[row * NODE_DIM + lane];
    float x1 = x[row * NODE_DIM + 64 + lane];
    float acc = b[lane];
#pragma unroll
    for (int k = 0; k < 64; ++k) acc = fmaf(__shfl(x0, k), wl[k * HID + lane], acc);
#pragma unroll
    for (int k = 0; k < 64; ++k) acc = fmaf(__shfl(x1, k), wl[(64 + k) * HID + lane], acc);
    h[row * HID + lane] = fmaxf(acc, 0.f);
  }
}

// ---- degree count (float atomics; exact for counts < 2^24) ----
__global__ void k_deg(const int* __restrict__ dst, float* __restrict__ deg) {
  int stride = gridDim.x * blockDim.x;
  for (int e = blockIdx.x * blockDim.x + threadIdx.x; e < N_EDGES; e += stride)
    atomicAdd(&deg[dst[e]], 1.f);
}

__global__ void k_invdeg(const float* __restrict__ deg, float* __restrict__ inv) {
  int i = blockIdx.x * blockDim.x + threadIdx.x;
  if (i < N_NODES) {
    float d = deg[i];
    inv[i] = d > 0.f ? 1.f / d : 0.f;  // == where(deg>0, 1/max(deg,1), 0)
  }
}

// ---- scatter: agg[dst] += h[src]; wave per edge, lane = feature ----
__global__ void k_scatter(const int* __restrict__ src, const int* __restrict__ dst,
                          const float* __restrict__ h, float* __restrict__ agg) {
  const int lane = threadIdx.x & 63;
  int gw = (blockIdx.x * blockDim.x + threadIdx.x) >> 6;
  int nw = (gridDim.x * blockDim.x) >> 6;
  for (int e = gw; e < N_EDGES; e += nw) {
    int s = src[e], d = dst[e];
    atomicAdd(&agg[d * HID + lane], h[s * HID + lane]);
  }
}

// ---- SAGE layer: hout = relu(agg*inv @ lw + lb + h @ rw), wave per row ----
__global__ void k_update(const float* __restrict__ agg, const float* __restrict__ inv,
                         const float* __restrict__ h,
                         const float* __restrict__ lw, const float* __restrict__ lb,
                         const float* __restrict__ rw, float* __restrict__ hout) {
  __shared__ float lwl[HID * HID], rwl[HID * HID];
  for (int i = threadIdx.x; i < HID * HID; i += blockDim.x) {
    lwl[i] = lw[i];
    rwl[i] = rw[i];
  }
  __syncthreads();
  const int lane = threadIdx.x & 63;
  const int wid = threadIdx.x >> 6;
  const int wpb = blockDim.x >> 6;
  const int nw = gridDim.x * wpb;
  for (int row = blockIdx.x * wpb + wid; row < N_NODES; row += nw) {
    float a = agg[row * HID + lane] * inv[row];
    float hr = h[row * HID + lane];
    float acc = lb[lane];
#pragma unroll
    for (int k = 0; k < 64; ++k) {
      acc = fmaf(__shfl(a, k), lwl[k * HID + lane], acc);
      acc = fmaf(__shfl(hr, k), rwl[k * HID + lane], acc);
    }
    hout[row * HID + lane] = fmaxf(acc, 0.f);
  }
}

// ---- finalize: copy h to output + bf16 copy for the MFMA edge head ----
__global__ void k_final_h(const float* __restrict__ h, float* __restrict__ out_h,
                          unsigned short* __restrict__ hbf) {
  int stride = gridDim.x * blockDim.x;
  for (int i = blockIdx.x * blockDim.x + threadIdx.x; i < N_NODES * HID; i += stride) {
    float v = h[i];
    out_h[i] = v;
    hbf[i] = f2bf(v);
  }
}

// ---- pack W1 [128][64] into MFMA B-frag order ----
// w1p[((kt*4+ct)*64+lane)*8+j] = bf16(W1[kt*32 + (lane>>4)*8 + j][ct*16 + (lane&15)])
__global__ void k_pack_w1(const float* __restrict__ w1, unsigned short* __restrict__ w1p) {
  int i = blockIdx.x * blockDim.x + threadIdx.x;
  if (i >= 2 * HID * HID) return;
  int j = i & 7;
  int lane = (i >> 3) & 63;
  int ct = (i >> 9) & 3;
  int kt = i >> 11;
  int k = kt * 32 + (lane >> 4) * 8 + j;
  int c = ct * 16 + (lane & 15);
  w1p[i] = f2bf(w1[k * HID + c]);
}

// ---- edge head: wave per 16 edges, bf16 MFMA [16x128]@[128x64] ----
__global__ void k_edge_head(const int* __restrict__ src, const int* __restrict__ dst,
                            const unsigned short* __restrict__ hbf,
                            const bf16x8* __restrict__ w1p,
                            const float* __restrict__ b1, const float* __restrict__ w2,
                            const float* __restrict__ b2, float* __restrict__ scores) {
  const int lane = threadIdx.x & 63;
  const int wid = threadIdx.x >> 6;
  const int wpb = blockDim.x >> 6;
  const int nw = gridDim.x * wpb;
  const int er = lane & 15;  // A-frag row = edge-in-tile; also C column index
  const int kb = lane >> 4;  // k sub-block
  const int ntiles = N_EDGES / 16;
  for (int tile = blockIdx.x * wpb + wid; tile < ntiles; tile += nw) {
    int e = tile * 16 + er;
    int s = src[e], d = dst[e];
    f32x4 acc0 = {0.f, 0.f, 0.f, 0.f}, acc1 = acc0, acc2 = acc0, acc3 = acc0;
#pragma unroll
    for (int kt = 0; kt < 4; ++kt) {
      int row = (kt < 2) ? s : d;
      int koff = (kt & 1) * 32;
      bf16x8 a = *reinterpret_cast<const bf16x8*>(hbf + (size_t)row * HID + koff + kb * 8);
      acc0 = __builtin_amdgcn_mfma_f32_16x16x32_bf16(a, w1p[(kt * 4 + 0) * 64 + lane], acc0, 0, 0, 0);
      acc1 = __builtin_amdgcn_mfma_f32_16x16x32_bf16(a, w1p[(kt * 4 + 1) * 64 + lane], acc1, 0, 0, 0);
      acc2 = __builtin_amdgcn_mfma_f32_16x16x32_bf16(a, w1p[(kt * 4 + 2) * 64 + lane], acc2, 0, 0, 0);
      acc3 = __builtin_amdgcn_mfma_f32_16x16x32_bf16(a, w1p[(kt * 4 + 3) * 64 + lane], acc3, 0, 0, 0);
    }
    // epilogue: lane holds C[row=kb*4+r][col=f*16+er]; hid=relu(C+b1), dot w2
    float part[4] = {0.f, 0.f, 0.f, 0.f};
#define EPI(ACC, F)                                              \
  {                                                              \
    int c = (F) * 16 + er;                                       \
    float b1c = b1[c], w2c = w2[c];                              \
    part[0] += fmaxf(ACC[0] + b1c, 0.f) * w2c;                   \
    part[1] += fmaxf(ACC[1] + b1c, 0.f) * w2c;                   \
    part[2] += fmaxf(ACC[2] + b1c, 0.f) * w2c;                   \
    part[3] += fmaxf(ACC[3] + b1c, 0.f) * w2c;                   \
  }
    EPI(acc0, 0) EPI(acc1, 1) EPI(acc2, 2) EPI(acc3, 3)
#undef EPI
#pragma unroll
    for (int off = 1; off < 16; off <<= 1) {
      part[0] += __shfl_xor(part[0], off);
      part[1] += __shfl_xor(part[1], off);
      part[2] += __shfl_xor(part[2], off);
      part[3] += __shfl_xor(part[3], off);
    }
    if (er == 0) {
      float bb = b2[0];
#pragma unroll
      for (int r = 0; r < 4; ++r) {
        int eo = tile * 16 + kb * 4 + r;
        float logit = part[r] + bb;
        scores[eo] = 1.f / (1.f + __expf(-logit));
      }
    }
  }
}

// ---- mean of scores ----
__global__ void k_mean(const float* __restrict__ scores, float* __restrict__ out) {
  float s = 0.f;
  int stride = gridDim.x * blockDim.x;
  for (int i = blockIdx.x * blockDim.x + threadIdx.x; i < N_EDGES; i += stride) s += scores[i];
#pragma unroll
  for (int off = 32; off; off >>= 1) s += __shfl_xor(s, off);
  __shared__ float bs[8];
  int lane = threadIdx.x & 63, wid = threadIdx.x >> 6;
  if (lane == 0) bs[wid] = s;
  __syncthreads();
  if (threadIdx.x == 0) {
    float t = 0.f;
    for (int i = 0; i < (int)(blockDim.x >> 6); ++i) t += bs[i];
    atomicAdd(out, t * (1.f / (float)N_EDGES));
  }
}

extern "C" void kernel_launch(void* const* d_in, const int* in_sizes, int n_in,
                              void* d_out, int out_size, void* d_ws, size_t ws_size,
                              hipStream_t stream) {
  const float* x = (const float*)d_in[0];
  const int* ei = (const int*)d_in[1];
  const int* src = ei;
  const int* dst = ei + N_EDGES;
  const float* enc_w = (const float*)d_in[3];
  const float* enc_b = (const float*)d_in[4];
  const float* conv_lw = (const float*)d_in[7];
  const float* conv_lb = (const float*)d_in[8];
  const float* conv_rw = (const float*)d_in[9];
  const float* eh_w1 = (const float*)d_in[10];
  const float* eh_b1 = (const float*)d_in[11];
  const float* eh_w2 = (const float*)d_in[12];
  const float* eh_b2 = (const float*)d_in[13];

  float* out_scores = (float*)d_out;
  float* out_mean = out_scores + N_EDGES;
  float* out_h = out_mean + 1;

  float* ws = (float*)d_ws;
  float* h0 = ws;                          // 6.4M f32
  float* h1 = h0 + N_NODES * HID;          // 6.4M f32
  float* agg = h1 + N_NODES * HID;         // 6.4M f32
  float* deg = agg + N_NODES * HID;        // 100K f32
  float* inv = deg + N_NODES;              // 100K f32
  unsigned short* hbf = (unsigned short*)(inv + N_NODES);  // 6.4M bf16 (16B-aligned)
  unsigned short* w1p = hbf + N_NODES * HID;               // 8192 bf16

  hipMemsetAsync(deg, 0, N_NODES * sizeof(float), stream);
  hipMemsetAsync(agg, 0, N_NODES * HID * sizeof(float), stream);

  k_encode<<<2048, 256, 0, stream>>>(x, enc_w, enc_b, h0);
  k_deg<<<2048, 256, 0, stream>>>(dst, deg);
  k_invdeg<<<(N_NODES + 255) / 256, 256, 0, stream>>>(deg, inv);

  // layer 0: h0 -> h1
  k_scatter<<<2048, 256, 0, stream>>>(src, dst, h0, agg);
  k_update<<<2048, 256, 0, stream>>>(agg, inv, h0, conv_lw, conv_lb, conv_rw, h1);

  // layer 1: h1 -> h0
  hipMemsetAsync(agg, 0, N_NODES * HID * sizeof(float), stream);
  k_scatter<<<2048, 256, 0, stream>>>(src, dst, h1, agg);
  k_update<<<2048, 256, 0, stream>>>(agg, inv, h1, conv_lw + HID * HID, conv_lb + HID,
                                     conv_rw + HID * HID, h0);

  k_final_h<<<2048, 256, 0, stream>>>(h0, out_h, hbf);
  k_pack_w1<<<(2 * HID * HID + 255) / 256, 256, 0, stream>>>(eh_w1, w1p);
  k_edge_head<<<2048, 256, 0, stream>>>(src, dst, hbf, (const bf16x8*)w1p, eh_b1, eh_w2,
                                        eh_b2, out_scores);
  hipMemsetAsync(out_mean, 0, sizeof(float), stream);
  k_mean<<<2048, 256, 0, stream>>>(out_scores, out_mean);
}

// Round 2
// 587.340 us; speedup vs baseline: 2.6362x; 2.6362x over previous
//
#include <hip/hip_runtime.h>
#include <hip/hip_bf16.h>

#define N_NODES 100000
#define N_EDGES 1600000
#define HID 64
#define NODE_DIM 128
#define NCHUNK ((N_NODES + 1023) / 1024)

typedef __attribute__((ext_vector_type(8))) short bf16x8;
typedef __attribute__((ext_vector_type(8))) float f32x8;
typedef __attribute__((ext_vector_type(4))) float f32x4;

__device__ __forceinline__ unsigned short f2bf(float f) {
  __hip_bfloat16 h = __float2bfloat16(f);
  return *reinterpret_cast<unsigned short*>(&h);
}
__device__ __forceinline__ float bf2f(unsigned short u) {
  __hip_bfloat16 h = *reinterpret_cast<__hip_bfloat16*>(&u);
  return __bfloat162float(h);
}

// ---- pack W[K][64] (fp32) into MFMA B-frag order, hi/lo bf16 split ----
// out[((kt*4+ct)*64+lane)*8+j] = W[kt*32 + (lane>>4)*8 + j][ct*16 + (lane&15)]
__global__ void k_pack_hilo(const float* __restrict__ w, unsigned short* __restrict__ whi,
                            unsigned short* __restrict__ wlo, int kelems) {
  int i = blockIdx.x * blockDim.x + threadIdx.x;
  if (i >= kelems * HID) return;
  int j = i & 7;
  int lane = (i >> 3) & 63;
  int ct = (i >> 9) & 3;
  int kt = i >> 11;
  int k = kt * 32 + (lane >> 4) * 8 + j;
  int c = ct * 16 + (lane & 15);
  float v = w[k * HID + c];
  unsigned short hi = f2bf(v);
  whi[i] = hi;
  wlo[i] = f2bf(v - bf2f(hi));
}

// ---- plain bf16 pack for edge head W1 [128][64] ----
__global__ void k_pack_w1(const float* __restrict__ w1, unsigned short* __restrict__ w1p) {
  int i = blockIdx.x * blockDim.x + threadIdx.x;
  if (i >= 2 * HID * HID) return;
  int j = i & 7;
  int lane = (i >> 3) & 63;
  int ct = (i >> 9) & 3;
  int kt = i >> 11;
  int k = kt * 32 + (lane >> 4) * 8 + j;
  int c = ct * 16 + (lane & 15);
  w1p[i] = f2bf(w1[k * HID + c]);
}

// ---- encoder: h = relu(x @ W + b) via MFMA, wave per 16-row tile ----
__global__ void k_encode_mfma(const float* __restrict__ x, const bf16x8* __restrict__ whi,
                              const bf16x8* __restrict__ wlo, const float* __restrict__ b,
                              float* __restrict__ h) {
  const int lane = threadIdx.x & 63;
  const int er = lane & 15, kb = lane >> 4;
  int gw = (blockIdx.x * blockDim.x + threadIdx.x) >> 6;
  int nw = (gridDim.x * blockDim.x) >> 6;
  const int ntiles = N_NODES / 16;
  for (int tile = gw; tile < ntiles; tile += nw) {
    int R = tile * 16;
    f32x4 acc[4] = {{0.f, 0.f, 0.f, 0.f}, {0.f, 0.f, 0.f, 0.f}, {0.f, 0.f, 0.f, 0.f}, {0.f, 0.f, 0.f, 0.f}};
#pragma unroll
    for (int kt = 0; kt < 4; ++kt) {
      f32x8 xv = *reinterpret_cast<const f32x8*>(x + (size_t)(R + er) * NODE_DIM + kt * 32 + kb * 8);
      bf16x8 ahi, alo;
#pragma unroll
      for (int j = 0; j < 8; ++j) {
        unsigned short hi = f2bf(xv[j]);
        ahi[j] = (short)hi;
        alo[j] = (short)f2bf(xv[j] - bf2f(hi));
      }
#pragma unroll
      for (int ct = 0; ct < 4; ++ct) {
        bf16x8 bh = whi[(kt * 4 + ct) * 64 + lane];
        bf16x8 bl = wlo[(kt * 4 + ct) * 64 + lane];
        acc[ct] = __builtin_amdgcn_mfma_f32_16x16x32_bf16(ahi, bh, acc[ct], 0, 0, 0);
        acc[ct] = __builtin_amdgcn_mfma_f32_16x16x32_bf16(alo, bh, acc[ct], 0, 0, 0);
        acc[ct] = __builtin_amdgcn_mfma_f32_16x16x32_bf16(ahi, bl, acc[ct], 0, 0, 0);
      }
    }
#pragma unroll
    for (int ct = 0; ct < 4; ++ct) {
      float bb = b[ct * 16 + er];
#pragma unroll
      for (int r = 0; r < 4; ++r)
        h[(size_t)(R + kb * 4 + r) * HID + ct * 16 + er] = fmaxf(acc[ct][r] + bb, 0.f);
    }
  }
}

// ---- degree count (int atomics) ----
__global__ void k_deg(const int* __restrict__ dst, int* __restrict__ deg) {
  int stride = gridDim.x * blockDim.x;
  for (int e = blockIdx.x * blockDim.x + threadIdx.x; e < N_EDGES; e += stride)
    atomicAdd(&deg[dst[e]], 1);
}

// ---- block-wise inclusive scan of deg -> off (inclusive), block totals ----
__global__ void k_scan_partial(const int* __restrict__ deg, int* __restrict__ off,
                               int* __restrict__ bsum) {
  int b = blockIdx.x;
  int i = b * 1024 + threadIdx.x;
  int v = (i < N_NODES) ? deg[i] : 0;
  int lane = threadIdx.x & 63, wid = threadIdx.x >> 6;
  int s = v;
#pragma unroll
  for (int d = 1; d < 64; d <<= 1) {
    int t = __shfl_up(s, d);
    if (lane >= d) s += t;
  }
  __shared__ int wsum[16];
  if (lane == 63) wsum[wid] = s;
  __syncthreads();
  if (wid == 0 && lane < 16) {
    int t = wsum[lane];
#pragma unroll
    for (int d = 1; d < 16; d <<= 1) {
      int u = __shfl_up(t, d);
      if (lane >= d) t += u;
    }
    wsum[lane] = t;
  }
  __syncthreads();
  int incl = s + (wid > 0 ? wsum[wid - 1] : 0);
  if (i < N_NODES) off[i] = incl;
  if (threadIdx.x == 1023) bsum[b] = incl;
}

__global__ void k_scan_bsums(const int* __restrict__ bsum, int* __restrict__ bpre,
                             int* __restrict__ off) {
  if (threadIdx.x == 0 && blockIdx.x == 0) {
    int run = 0;
    for (int c = 0; c < NCHUNK; ++c) {
      bpre[c] = run;
      run += bsum[c];
    }
    off[N_NODES] = run;
  }
}

// ---- convert inclusive->exclusive + add block prefix; init cursor ----
__global__ void k_scan_final(const int* __restrict__ deg, const int* __restrict__ bpre,
                             int* __restrict__ off, int* __restrict__ cursor) {
  int i = blockIdx.x * blockDim.x + threadIdx.x;
  if (i < N_NODES) {
    int e = off[i] - deg[i] + bpre[i >> 10];
    off[i] = e;
    cursor[i] = e;
  }
}

// ---- CSR fill: csr[slot] = src for each (dst) bucket ----
__global__ void k_fill(const int* __restrict__ src, const int* __restrict__ dst,
                       int* __restrict__ cursor, int* __restrict__ csr) {
  int stride = gridDim.x * blockDim.x;
  for (int e = blockIdx.x * blockDim.x + threadIdx.x; e < N_EDGES; e += stride) {
    int d = dst[e];
    int pos = atomicAdd(&cursor[d], 1);
    csr[pos] = src[e];
  }
}

// ---- mean-aggregate: wave per node, lane = feature ----
__global__ void k_agg(const int* __restrict__ off, const int* __restrict__ csr,
                      const float* __restrict__ h, float* __restrict__ agg) {
  const int lane = threadIdx.x & 63;
  int gw = (blockIdx.x * blockDim.x + threadIdx.x) >> 6;
  int nw = (gridDim.x * blockDim.x) >> 6;
  for (int n = gw; n < N_NODES; n += nw) {
    int s0 = off[n], s1 = off[n + 1];
    float acc = 0.f;
    int i = s0;
    for (; i + 4 <= s1; i += 4) {
      int a = csr[i], b = csr[i + 1], c = csr[i + 2], d = csr[i + 3];
      float v0 = h[(size_t)a * HID + lane];
      float v1 = h[(size_t)b * HID + lane];
      float v2 = h[(size_t)c * HID + lane];
      float v3 = h[(size_t)d * HID + lane];
      acc += v0 + v1 + v2 + v3;
    }
    for (; i < s1; ++i) acc += h[(size_t)csr[i] * HID + lane];
    int cnt = s1 - s0;
    agg[(size_t)n * HID + lane] = cnt > 0 ? acc * (1.f / (float)cnt) : 0.f;
  }
}

// ---- SAGE update: hout = relu(agg @ lw + lb + h @ rw) via MFMA ----
__global__ void k_update_mfma(const float* __restrict__ agg, const float* __restrict__ h,
                              const bf16x8* __restrict__ lwhi, const bf16x8* __restrict__ lwlo,
                              const float* __restrict__ lb,
                              const bf16x8* __restrict__ rwhi, const bf16x8* __restrict__ rwlo,
                              float* __restrict__ hout) {
  const int lane = threadIdx.x & 63;
  const int er = lane & 15, kb = lane >> 4;
  int gw = (blockIdx.x * blockDim.x + threadIdx.x) >> 6;
  int nw = (gridDim.x * blockDim.x) >> 6;
  const int ntiles = N_NODES / 16;
  for (int tile = gw; tile < ntiles; tile += nw) {
    int R = tile * 16;
    f32x4 acc[4] = {{0.f, 0.f, 0.f, 0.f}, {0.f, 0.f, 0.f, 0.f}, {0.f, 0.f, 0.f, 0.f}, {0.f, 0.f, 0.f, 0.f}};
#pragma unroll
    for (int kt = 0; kt < 2; ++kt) {
      f32x8 av = *reinterpret_cast<const f32x8*>(agg + (size_t)(R + er) * HID + kt * 32 + kb * 8);
      f32x8 hv = *reinterpret_cast<const f32x8*>(h + (size_t)(R + er) * HID + kt * 32 + kb * 8);
      bf16x8 ahi, alo, hhi, hlo;
#pragma unroll
      for (int j = 0; j < 8; ++j) {
        unsigned short u = f2bf(av[j]);
        ahi[j] = (short)u;
        alo[j] = (short)f2bf(av[j] - bf2f(u));
        unsigned short w = f2bf(hv[j]);
        hhi[j] = (short)w;
        hlo[j] = (short)f2bf(hv[j] - bf2f(w));
      }
#pragma unroll
      for (int ct = 0; ct < 4; ++ct) {
        bf16x8 lh = lwhi[(kt * 4 + ct) * 64 + lane];
        bf16x8 ll = lwlo[(kt * 4 + ct) * 64 + lane];
        bf16x8 rh = rwhi[(kt * 4 + ct) * 64 + lane];
        bf16x8 rl = rwlo[(kt * 4 + ct) * 64 + lane];
        acc[ct] = __builtin_amdgcn_mfma_f32_16x16x32_bf16(ahi, lh, acc[ct], 0, 0, 0);
        acc[ct] = __builtin_amdgcn_mfma_f32_16x16x32_bf16(alo, lh, acc[ct], 0, 0, 0);
        acc[ct] = __builtin_amdgcn_mfma_f32_16x16x32_bf16(ahi, ll, acc[ct], 0, 0, 0);
        acc[ct] = __builtin_amdgcn_mfma_f32_16x16x32_bf16(hhi, rh, acc[ct], 0, 0, 0);
        acc[ct] = __builtin_amdgcn_mfma_f32_16x16x32_bf16(hlo, rh, acc[ct], 0, 0, 0);
        acc[ct] = __builtin_amdgcn_mfma_f32_16x16x32_bf16(hhi, rl, acc[ct], 0, 0, 0);
      }
    }
#pragma unroll
    for (int ct = 0; ct < 4; ++ct) {
      float bb = lb[ct * 16 + er];
#pragma unroll
      for (int r = 0; r < 4; ++r)
        hout[(size_t)(R + kb * 4 + r) * HID + ct * 16 + er] = fmaxf(acc[ct][r] + bb, 0.f);
    }
  }
}

// ---- finalize: copy h to output + bf16 copy for the MFMA edge head ----
__global__ void k_final_h(const float* __restrict__ h, float* __restrict__ out_h,
                          unsigned short* __restrict__ hbf) {
  int stride = gridDim.x * blockDim.x;
  for (int i = blockIdx.x * blockDim.x + threadIdx.x; i < N_NODES * HID; i += stride) {
    float v = h[i];
    out_h[i] = v;
    hbf[i] = f2bf(v);
  }
}

// ---- edge head: wave per 16 edges, bf16 MFMA [16x128]@[128x64] ----
__global__ void k_edge_head(const int* __restrict__ src, const int* __restrict__ dst,
                            const unsigned short* __restrict__ hbf,
                            const bf16x8* __restrict__ w1p,
                            const float* __restrict__ b1, const float* __restrict__ w2,
                            const float* __restrict__ b2, float* __restrict__ scores) {
  const int lane = threadIdx.x & 63;
  const int wid = threadIdx.x >> 6;
  const int wpb = blockDim.x >> 6;
  const int nw = gridDim.x * wpb;
  const int er = lane & 15;
  const int kb = lane >> 4;
  const int ntiles = N_EDGES / 16;
  for (int tile = blockIdx.x * wpb + wid; tile < ntiles; tile += nw) {
    int e = tile * 16 + er;
    int s = src[e], d = dst[e];
    f32x4 acc0 = {0.f, 0.f, 0.f, 0.f}, acc1 = acc0, acc2 = acc0, acc3 = acc0;
#pragma unroll
    for (int kt = 0; kt < 4; ++kt) {
      int row = (kt < 2) ? s : d;
      int koff = (kt & 1) * 32;
      bf16x8 a = *reinterpret_cast<const bf16x8*>(hbf + (size_t)row * HID + koff + kb * 8);
      acc0 = __builtin_amdgcn_mfma_f32_16x16x32_bf16(a, w1p[(kt * 4 + 0) * 64 + lane], acc0, 0, 0, 0);
      acc1 = __builtin_amdgcn_mfma_f32_16x16x32_bf16(a, w1p[(kt * 4 + 1) * 64 + lane], acc1, 0, 0, 0);
      acc2 = __builtin_amdgcn_mfma_f32_16x16x32_bf16(a, w1p[(kt * 4 + 2) * 64 + lane], acc2, 0, 0, 0);
      acc3 = __builtin_amdgcn_mfma_f32_16x16x32_bf16(a, w1p[(kt * 4 + 3) * 64 + lane], acc3, 0, 0, 0);
    }
    float part[4] = {0.f, 0.f, 0.f, 0.f};
#define EPI(ACC, F)                                              \
  {                                                              \
    int c = (F) * 16 + er;                                       \
    float b1c = b1[c], w2c = w2[c];                              \
    part[0] += fmaxf(ACC[0] + b1c, 0.f) * w2c;                   \
    part[1] += fmaxf(ACC[1] + b1c, 0.f) * w2c;                   \
    part[2] += fmaxf(ACC[2] + b1c, 0.f) * w2c;                   \
    part[3] += fmaxf(ACC[3] + b1c, 0.f) * w2c;                   \
  }
    EPI(acc0, 0) EPI(acc1, 1) EPI(acc2, 2) EPI(acc3, 3)
#undef EPI
#pragma unroll
    for (int off = 1; off < 16; off <<= 1) {
      part[0] += __shfl_xor(part[0], off);
      part[1] += __shfl_xor(part[1], off);
      part[2] += __shfl_xor(part[2], off);
      part[3] += __shfl_xor(part[3], off);
    }
    if (er == 0) {
      float bb = b2[0];
#pragma unroll
      for (int r = 0; r < 4; ++r) {
        int eo = tile * 16 + kb * 4 + r;
        float logit = part[r] + bb;
        scores[eo] = 1.f / (1.f + __expf(-logit));
      }
    }
  }
}

// ---- mean of scores ----
__global__ void k_mean(const float* __restrict__ scores, float* __restrict__ out) {
  float s = 0.f;
  int stride = gridDim.x * blockDim.x;
  for (int i = blockIdx.x * blockDim.x + threadIdx.x; i < N_EDGES; i += stride) s += scores[i];
#pragma unroll
  for (int off = 32; off; off >>= 1) s += __shfl_xor(s, off);
  __shared__ float bs[8];
  int lane = threadIdx.x & 63, wid = threadIdx.x >> 6;
  if (lane == 0) bs[wid] = s;
  __syncthreads();
  if (threadIdx.x == 0) {
    float t = 0.f;
    for (int i = 0; i < (int)(blockDim.x >> 6); ++i) t += bs[i];
    atomicAdd(out, t * (1.f / (float)N_EDGES));
  }
}

extern "C" void kernel_launch(void* const* d_in, const int* in_sizes, int n_in,
                              void* d_out, int out_size, void* d_ws, size_t ws_size,
                              hipStream_t stream) {
  const float* x = (const float*)d_in[0];
  const int* ei = (const int*)d_in[1];
  const int* src = ei;
  const int* dst = ei + N_EDGES;
  const float* enc_w = (const float*)d_in[3];
  const float* enc_b = (const float*)d_in[4];
  const float* conv_lw = (const float*)d_in[7];
  const float* conv_lb = (const float*)d_in[8];
  const float* conv_rw = (const float*)d_in[9];
  const float* eh_w1 = (const float*)d_in[10];
  const float* eh_b1 = (const float*)d_in[11];
  const float* eh_w2 = (const float*)d_in[12];
  const float* eh_b2 = (const float*)d_in[13];

  float* out_scores = (float*)d_out;
  float* out_mean = out_scores + N_EDGES;
  float* out_h = out_mean + 1;

  float* ws = (float*)d_ws;
  float* h0 = ws;                                   // 6.4M f32
  float* h1 = h0 + N_NODES * HID;                   // 6.4M f32
  float* agg = h1 + N_NODES * HID;                  // 6.4M f32
  int* deg = (int*)(agg + N_NODES * HID);           // 100K int
  int* off = deg + N_NODES;                         // 100K+1 int
  int* cursor = off + N_NODES + 1;                  // 100K int
  int* bsum = cursor + N_NODES;                     // NCHUNK
  int* bpre = bsum + NCHUNK;                        // NCHUNK
  int* csr = bpre + NCHUNK + 2;                     // 1.6M int
  unsigned short* hbf = (unsigned short*)(csr + N_EDGES);  // 6.4M bf16
  unsigned short* w1p = hbf + (size_t)N_NODES * HID;       // 8K bf16
  unsigned short* encwh = w1p + 8192;               // 8K bf16
  unsigned short* encwl = encwh + 8192;             // 8K
  unsigned short* cw = encwl + 8192;                // conv packs: 2 layers x {lwhi,lwlo,rwhi,rwlo} x 4096
  unsigned short* lwhi0 = cw,        * lwlo0 = cw + 4096,  * rwhi0 = cw + 8192,  * rwlo0 = cw + 12288;
  unsigned short* lwhi1 = cw + 16384, * lwlo1 = cw + 20480, * rwhi1 = cw + 24576, * rwlo1 = cw + 28672;

  hipMemsetAsync(deg, 0, N_NODES * sizeof(int), stream);

  // weight packing (tiny)
  k_pack_hilo<<<(NODE_DIM * HID + 255) / 256, 256, 0, stream>>>(enc_w, encwh, encwl, NODE_DIM);
  k_pack_hilo<<<(HID * HID + 255) / 256, 256, 0, stream>>>(conv_lw, lwhi0, lwlo0, HID);
  k_pack_hilo<<<(HID * HID + 255) / 256, 256, 0, stream>>>(conv_rw, rwhi0, rwlo0, HID);
  k_pack_hilo<<<(HID * HID + 255) / 256, 256, 0, stream>>>(conv_lw + HID * HID, lwhi1, lwlo1, HID);
  k_pack_hilo<<<(HID * HID + 255) / 256, 256, 0, stream>>>(conv_rw + HID * HID, rwhi1, rwlo1, HID);
  k_pack_w1<<<(2 * HID * HID + 255) / 256, 256, 0, stream>>>(eh_w1, w1p);

  // CSR build
  k_deg<<<2048, 256, 0, stream>>>(dst, deg);
  k_scan_partial<<<NCHUNK, 1024, 0, stream>>>(deg, off, bsum);
  k_scan_bsums<<<1, 64, 0, stream>>>(bsum, bpre, off);
  k_scan_final<<<(N_NODES + 255) / 256, 256, 0, stream>>>(deg, bpre, off, cursor);
  k_fill<<<2048, 256, 0, stream>>>(src, dst, cursor, csr);

  // encoder
  k_encode_mfma<<<1024, 256, 0, stream>>>(x, (const bf16x8*)encwh, (const bf16x8*)encwl, enc_b, h0);

  // layer 0: h0 -> h1
  k_agg<<<2048, 256, 0, stream>>>(off, csr, h0, agg);
  k_update_mfma<<<1024, 256, 0, stream>>>(agg, h0, (const bf16x8*)lwhi0, (const bf16x8*)lwlo0,
                                          conv_lb, (const bf16x8*)rwhi0, (const bf16x8*)rwlo0, h1);

  // layer 1: h1 -> h0
  k_agg<<<2048, 256, 0, stream>>>(off, csr, h1, agg);
  k_update_mfma<<<1024, 256, 0, stream>>>(agg, h1, (const bf16x8*)lwhi1, (const bf16x8*)lwlo1,
                                          conv_lb + HID, (const bf16x8*)rwhi1, (const bf16x8*)rwlo1, h0);

  k_final_h<<<2048, 256, 0, stream>>>(h0, out_h, hbf);
  k_edge_head<<<2048, 256, 0, stream>>>(src, dst, hbf, (const bf16x8*)w1p, eh_b1, eh_w2,
                                        eh_b2, out_scores);
  hipMemsetAsync(out_mean, 0, sizeof(float), stream);
  k_mean<<<2048, 256, 0, stream>>>(out_scores, out_mean);
}

// Round 3
// 506.811 us; speedup vs baseline: 3.0551x; 1.1589x over previous
//
#include <hip/hip_runtime.h>
#include <hip/hip_bf16.h>

#define N_NODES 100000
#define N_EDGES 1600000
#define HID 64
#define NODE_DIM 128
#define NCHUNK ((N_NODES + 1023) / 1024)
#define NPB 512                              // nodes per bucket (dst>>9)
#define NBUCK ((N_NODES + NPB - 1) / NPB)    // 196
#define EPB_A 4096                           // edges per partition block

typedef __attribute__((ext_vector_type(8))) short bf16x8;
typedef __attribute__((ext_vector_type(8))) float f32x8;
typedef __attribute__((ext_vector_type(4))) float f32x4;

__device__ __forceinline__ unsigned short f2bf(float f) {
  __hip_bfloat16 h = __float2bfloat16(f);
  return *reinterpret_cast<unsigned short*>(&h);
}
__device__ __forceinline__ float bf2f(unsigned short u) {
  __hip_bfloat16 h = *reinterpret_cast<__hip_bfloat16*>(&u);
  return __bfloat162float(h);
}

// ---- pack W[K][64] (fp32) into MFMA B-frag order, hi/lo bf16 split ----
__global__ void k_pack_hilo(const float* __restrict__ w, unsigned short* __restrict__ whi,
                            unsigned short* __restrict__ wlo, int kelems) {
  int i = blockIdx.x * blockDim.x + threadIdx.x;
  if (i >= kelems * HID) return;
  int j = i & 7;
  int lane = (i >> 3) & 63;
  int ct = (i >> 9) & 3;
  int kt = i >> 11;
  int k = kt * 32 + (lane >> 4) * 8 + j;
  int c = ct * 16 + (lane & 15);
  float v = w[k * HID + c];
  unsigned short hi = f2bf(v);
  whi[i] = hi;
  wlo[i] = f2bf(v - bf2f(hi));
}

// ---- plain bf16 pack for edge head W1 [128][64] ----
__global__ void k_pack_w1(const float* __restrict__ w1, unsigned short* __restrict__ w1p) {
  int i = blockIdx.x * blockDim.x + threadIdx.x;
  if (i >= 2 * HID * HID) return;
  int j = i & 7;
  int lane = (i >> 3) & 63;
  int ct = (i >> 9) & 3;
  int kt = i >> 11;
  int k = kt * 32 + (lane >> 4) * 8 + j;
  int c = ct * 16 + (lane & 15);
  w1p[i] = f2bf(w1[k * HID + c]);
}

// ---- encoder: h = relu(x @ W + b) via MFMA; writes f32 h + bf16 twin ----
__global__ void k_encode_mfma(const float* __restrict__ x, const bf16x8* __restrict__ whi,
                              const bf16x8* __restrict__ wlo, const float* __restrict__ b,
                              float* __restrict__ h, unsigned short* __restrict__ hbf) {
  const int lane = threadIdx.x & 63;
  const int er = lane & 15, kb = lane >> 4;
  int gw = (blockIdx.x * blockDim.x + threadIdx.x) >> 6;
  int nw = (gridDim.x * blockDim.x) >> 6;
  const int ntiles = N_NODES / 16;
  for (int tile = gw; tile < ntiles; tile += nw) {
    int R = tile * 16;
    f32x4 acc[4] = {{0.f, 0.f, 0.f, 0.f}, {0.f, 0.f, 0.f, 0.f}, {0.f, 0.f, 0.f, 0.f}, {0.f, 0.f, 0.f, 0.f}};
#pragma unroll
    for (int kt = 0; kt < 4; ++kt) {
      f32x8 xv = *reinterpret_cast<const f32x8*>(x + (size_t)(R + er) * NODE_DIM + kt * 32 + kb * 8);
      bf16x8 ahi, alo;
#pragma unroll
      for (int j = 0; j < 8; ++j) {
        unsigned short hi = f2bf(xv[j]);
        ahi[j] = (short)hi;
        alo[j] = (short)f2bf(xv[j] - bf2f(hi));
      }
#pragma unroll
      for (int ct = 0; ct < 4; ++ct) {
        bf16x8 bh = whi[(kt * 4 + ct) * 64 + lane];
        bf16x8 bl = wlo[(kt * 4 + ct) * 64 + lane];
        acc[ct] = __builtin_amdgcn_mfma_f32_16x16x32_bf16(ahi, bh, acc[ct], 0, 0, 0);
        acc[ct] = __builtin_amdgcn_mfma_f32_16x16x32_bf16(alo, bh, acc[ct], 0, 0, 0);
        acc[ct] = __builtin_amdgcn_mfma_f32_16x16x32_bf16(ahi, bl, acc[ct], 0, 0, 0);
      }
    }
#pragma unroll
    for (int ct = 0; ct < 4; ++ct) {
      float bb = b[ct * 16 + er];
#pragma unroll
      for (int r = 0; r < 4; ++r) {
        float v = fmaxf(acc[ct][r] + bb, 0.f);
        size_t idx = (size_t)(R + kb * 4 + r) * HID + ct * 16 + er;
        h[idx] = v;
        hbf[idx] = f2bf(v);
      }
    }
  }
}

// ---- degree count ----
__global__ void k_deg(const int* __restrict__ dst, int* __restrict__ deg) {
  int stride = gridDim.x * blockDim.x;
  for (int e = blockIdx.x * blockDim.x + threadIdx.x; e < N_EDGES; e += stride)
    atomicAdd(&deg[dst[e]], 1);
}

// ---- block-wise inclusive scan of deg ----
__global__ void k_scan_partial(const int* __restrict__ deg, int* __restrict__ off,
                               int* __restrict__ bsum) {
  int b = blockIdx.x;
  int i = b * 1024 + threadIdx.x;
  int v = (i < N_NODES) ? deg[i] : 0;
  int lane = threadIdx.x & 63, wid = threadIdx.x >> 6;
  int s = v;
#pragma unroll
  for (int d = 1; d < 64; d <<= 1) {
    int t = __shfl_up(s, d);
    if (lane >= d) s += t;
  }
  __shared__ int wsum[16];
  if (lane == 63) wsum[wid] = s;
  __syncthreads();
  if (wid == 0 && lane < 16) {
    int t = wsum[lane];
#pragma unroll
    for (int d = 1; d < 16; d <<= 1) {
      int u = __shfl_up(t, d);
      if (lane >= d) t += u;
    }
    wsum[lane] = t;
  }
  __syncthreads();
  int incl = s + (wid > 0 ? wsum[wid - 1] : 0);
  if (i < N_NODES) off[i] = incl;
  if (threadIdx.x == 1023) bsum[b] = incl;
}

__global__ void k_scan_bsums(const int* __restrict__ bsum, int* __restrict__ bpre,
                             int* __restrict__ off) {
  if (threadIdx.x == 0 && blockIdx.x == 0) {
    int run = 0;
    for (int c = 0; c < NCHUNK; ++c) {
      bpre[c] = run;
      run += bsum[c];
    }
    off[N_NODES] = run;
  }
}

__global__ void k_scan_final(const int* __restrict__ deg, const int* __restrict__ bpre,
                             int* __restrict__ off) {
  int i = blockIdx.x * blockDim.x + threadIdx.x;
  if (i < N_NODES) off[i] = off[i] - deg[i] + bpre[i >> 10];
}

__global__ void k_init_bcur(const int* __restrict__ off, int* __restrict__ bcur) {
  int b = blockIdx.x * blockDim.x + threadIdx.x;
  if (b < NBUCK) bcur[b] = off[min(b * NPB, N_NODES)];
}

// ---- phase A: partition edges into dst-buckets (ranked contiguous writes) ----
__global__ void k_partition(const int* __restrict__ src, const int* __restrict__ dst,
                            int* __restrict__ bcur, unsigned long long* __restrict__ tbuf) {
  __shared__ int hist[NBUCK];
  for (int i = threadIdx.x; i < NBUCK; i += blockDim.x) hist[i] = 0;
  __syncthreads();
  int e0 = blockIdx.x * EPB_A;
#pragma unroll
  for (int k = 0; k < EPB_A / 256; ++k) {
    int e = e0 + k * 256 + threadIdx.x;
    if (e < N_EDGES) atomicAdd(&hist[dst[e] >> 9], 1);
  }
  __syncthreads();
  for (int b = threadIdx.x; b < NBUCK; b += blockDim.x) {
    int c = hist[b];
    hist[b] = c ? atomicAdd(&bcur[b], c) : 0;
  }
  __syncthreads();
#pragma unroll
  for (int k = 0; k < EPB_A / 256; ++k) {
    int e = e0 + k * 256 + threadIdx.x;
    if (e < N_EDGES) {
      int s = src[e], d = dst[e];
      int pos = atomicAdd(&hist[d >> 9], 1);
      tbuf[pos] = (unsigned long long)(unsigned)s | ((unsigned long long)(unsigned)d << 32);
    }
  }
}

// ---- phase B: within-bucket CSR fill (scatter window is L2-resident) ----
__global__ void k_bucket(const int* __restrict__ off, const unsigned long long* __restrict__ tbuf,
                         int* __restrict__ csr) {
  __shared__ int cur[NPB];
  int n0 = blockIdx.x * NPB;
  int n1 = min(n0 + NPB, N_NODES);
  for (int i = threadIdx.x; i < n1 - n0; i += blockDim.x) cur[i] = off[n0 + i];
  __syncthreads();
  int t0 = off[n0], t1 = off[n1];
  for (int t = t0 + threadIdx.x; t < t1; t += blockDim.x) {
    unsigned long long u = tbuf[t];
    int s = (int)(u & 0xffffffffULL);
    int d = (int)(u >> 32);
    int pos = atomicAdd(&cur[d - n0], 1);
    csr[pos] = s;
  }
}

// ---- mean-aggregate from bf16 twin: wave per node, lane = feature ----
__global__ void k_agg_bf(const int* __restrict__ off, const int* __restrict__ csr,
                         const unsigned short* __restrict__ hbf, float* __restrict__ agg) {
  const int lane = threadIdx.x & 63;
  int gw = (blockIdx.x * blockDim.x + threadIdx.x) >> 6;
  int nw = (gridDim.x * blockDim.x) >> 6;
  for (int n = gw; n < N_NODES; n += nw) {
    int s0 = off[n], s1 = off[n + 1];
    float acc = 0.f;
    int i = s0;
    for (; i + 4 <= s1; i += 4) {
      int a = csr[i], b = csr[i + 1], c = csr[i + 2], d = csr[i + 3];
      float v0 = bf2f(hbf[(size_t)a * HID + lane]);
      float v1 = bf2f(hbf[(size_t)b * HID + lane]);
      float v2 = bf2f(hbf[(size_t)c * HID + lane]);
      float v3 = bf2f(hbf[(size_t)d * HID + lane]);
      acc += v0 + v1 + v2 + v3;
    }
    for (; i < s1; ++i) acc += bf2f(hbf[(size_t)csr[i] * HID + lane]);
    int cnt = s1 - s0;
    agg[(size_t)n * HID + lane] = cnt > 0 ? acc * (1.f / (float)cnt) : 0.f;
  }
}

// ---- SAGE update via MFMA; optional bf16 twin output ----
__global__ void k_update_mfma(const float* __restrict__ agg, const float* __restrict__ h,
                              const bf16x8* __restrict__ lwhi, const bf16x8* __restrict__ lwlo,
                              const float* __restrict__ lb,
                              const bf16x8* __restrict__ rwhi, const bf16x8* __restrict__ rwlo,
                              float* __restrict__ hout, unsigned short* __restrict__ hbf_out) {
  const int lane = threadIdx.x & 63;
  const int er = lane & 15, kb = lane >> 4;
  int gw = (blockIdx.x * blockDim.x + threadIdx.x) >> 6;
  int nw = (gridDim.x * blockDim.x) >> 6;
  const int ntiles = N_NODES / 16;
  for (int tile = gw; tile < ntiles; tile += nw) {
    int R = tile * 16;
    f32x4 acc[4] = {{0.f, 0.f, 0.f, 0.f}, {0.f, 0.f, 0.f, 0.f}, {0.f, 0.f, 0.f, 0.f}, {0.f, 0.f, 0.f, 0.f}};
#pragma unroll
    for (int kt = 0; kt < 2; ++kt) {
      f32x8 av = *reinterpret_cast<const f32x8*>(agg + (size_t)(R + er) * HID + kt * 32 + kb * 8);
      f32x8 hv = *reinterpret_cast<const f32x8*>(h + (size_t)(R + er) * HID + kt * 32 + kb * 8);
      bf16x8 ahi, alo, hhi, hlo;
#pragma unroll
      for (int j = 0; j < 8; ++j) {
        unsigned short u = f2bf(av[j]);
        ahi[j] = (short)u;
        alo[j] = (short)f2bf(av[j] - bf2f(u));
        unsigned short w = f2bf(hv[j]);
        hhi[j] = (short)w;
        hlo[j] = (short)f2bf(hv[j] - bf2f(w));
      }
#pragma unroll
      for (int ct = 0; ct < 4; ++ct) {
        bf16x8 lh = lwhi[(kt * 4 + ct) * 64 + lane];
        bf16x8 ll = lwlo[(kt * 4 + ct) * 64 + lane];
        bf16x8 rh = rwhi[(kt * 4 + ct) * 64 + lane];
        bf16x8 rl = rwlo[(kt * 4 + ct) * 64 + lane];
        acc[ct] = __builtin_amdgcn_mfma_f32_16x16x32_bf16(ahi, lh, acc[ct], 0, 0, 0);
        acc[ct] = __builtin_amdgcn_mfma_f32_16x16x32_bf16(alo, lh, acc[ct], 0, 0, 0);
        acc[ct] = __builtin_amdgcn_mfma_f32_16x16x32_bf16(ahi, ll, acc[ct], 0, 0, 0);
        acc[ct] = __builtin_amdgcn_mfma_f32_16x16x32_bf16(hhi, rh, acc[ct], 0, 0, 0);
        acc[ct] = __builtin_amdgcn_mfma_f32_16x16x32_bf16(hlo, rh, acc[ct], 0, 0, 0);
        acc[ct] = __builtin_amdgcn_mfma_f32_16x16x32_bf16(hhi, rl, acc[ct], 0, 0, 0);
      }
    }
#pragma unroll
    for (int ct = 0; ct < 4; ++ct) {
      float bb = lb[ct * 16 + er];
#pragma unroll
      for (int r = 0; r < 4; ++r) {
        float v = fmaxf(acc[ct][r] + bb, 0.f);
        size_t idx = (size_t)(R + kb * 4 + r) * HID + ct * 16 + er;
        hout[idx] = v;
        if (hbf_out) hbf_out[idx] = f2bf(v);
      }
    }
  }
}

// ---- edge head: wave per 16 edges, bf16 MFMA [16x128]@[128x64] ----
__global__ void k_edge_head(const int* __restrict__ src, const int* __restrict__ dst,
                            const unsigned short* __restrict__ hbf,
                            const bf16x8* __restrict__ w1p,
                            const float* __restrict__ b1, const float* __restrict__ w2,
                            const float* __restrict__ b2, float* __restrict__ scores) {
  const int lane = threadIdx.x & 63;
  const int wid = threadIdx.x >> 6;
  const int wpb = blockDim.x >> 6;
  const int nw = gridDim.x * wpb;
  const int er = lane & 15;
  const int kb = lane >> 4;
  const int ntiles = N_EDGES / 16;
  for (int tile = blockIdx.x * wpb + wid; tile < ntiles; tile += nw) {
    int e = tile * 16 + er;
    int s = src[e], d = dst[e];
    f32x4 acc0 = {0.f, 0.f, 0.f, 0.f}, acc1 = acc0, acc2 = acc0, acc3 = acc0;
#pragma unroll
    for (int kt = 0; kt < 4; ++kt) {
      int row = (kt < 2) ? s : d;
      int koff = (kt & 1) * 32;
      bf16x8 a = *reinterpret_cast<const bf16x8*>(hbf + (size_t)row * HID + koff + kb * 8);
      acc0 = __builtin_amdgcn_mfma_f32_16x16x32_bf16(a, w1p[(kt * 4 + 0) * 64 + lane], acc0, 0, 0, 0);
      acc1 = __builtin_amdgcn_mfma_f32_16x16x32_bf16(a, w1p[(kt * 4 + 1) * 64 + lane], acc1, 0, 0, 0);
      acc2 = __builtin_amdgcn_mfma_f32_16x16x32_bf16(a, w1p[(kt * 4 + 2) * 64 + lane], acc2, 0, 0, 0);
      acc3 = __builtin_amdgcn_mfma_f32_16x16x32_bf16(a, w1p[(kt * 4 + 3) * 64 + lane], acc3, 0, 0, 0);
    }
    float part[4] = {0.f, 0.f, 0.f, 0.f};
#define EPI(ACC, F)                                              \
  {                                                              \
    int c = (F) * 16 + er;                                       \
    float b1c = b1[c], w2c = w2[c];                              \
    part[0] += fmaxf(ACC[0] + b1c, 0.f) * w2c;                   \
    part[1] += fmaxf(ACC[1] + b1c, 0.f) * w2c;                   \
    part[2] += fmaxf(ACC[2] + b1c, 0.f) * w2c;                   \
    part[3] += fmaxf(ACC[3] + b1c, 0.f) * w2c;                   \
  }
    EPI(acc0, 0) EPI(acc1, 1) EPI(acc2, 2) EPI(acc3, 3)
#undef EPI
#pragma unroll
    for (int off = 1; off < 16; off <<= 1) {
      part[0] += __shfl_xor(part[0], off);
      part[1] += __shfl_xor(part[1], off);
      part[2] += __shfl_xor(part[2], off);
      part[3] += __shfl_xor(part[3], off);
    }
    if (er == 0) {
      float bb = b2[0];
#pragma unroll
      for (int r = 0; r < 4; ++r) {
        int eo = tile * 16 + kb * 4 + r;
        float logit = part[r] + bb;
        scores[eo] = 1.f / (1.f + __expf(-logit));
      }
    }
  }
}

// ---- mean of scores ----
__global__ void k_mean(const float* __restrict__ scores, float* __restrict__ out) {
  float s = 0.f;
  int stride = gridDim.x * blockDim.x;
  for (int i = blockIdx.x * blockDim.x + threadIdx.x; i < N_EDGES; i += stride) s += scores[i];
#pragma unroll
  for (int off = 32; off; off >>= 1) s += __shfl_xor(s, off);
  __shared__ float bs[8];
  int lane = threadIdx.x & 63, wid = threadIdx.x >> 6;
  if (lane == 0) bs[wid] = s;
  __syncthreads();
  if (threadIdx.x == 0) {
    float t = 0.f;
    for (int i = 0; i < (int)(blockDim.x >> 6); ++i) t += bs[i];
    atomicAdd(out, t * (1.f / (float)N_EDGES));
  }
}

extern "C" void kernel_launch(void* const* d_in, const int* in_sizes, int n_in,
                              void* d_out, int out_size, void* d_ws, size_t ws_size,
                              hipStream_t stream) {
  const float* x = (const float*)d_in[0];
  const int* ei = (const int*)d_in[1];
  const int* src = ei;
  const int* dst = ei + N_EDGES;
  const float* enc_w = (const float*)d_in[3];
  const float* enc_b = (const float*)d_in[4];
  const float* conv_lw = (const float*)d_in[7];
  const float* conv_lb = (const float*)d_in[8];
  const float* conv_rw = (const float*)d_in[9];
  const float* eh_w1 = (const float*)d_in[10];
  const float* eh_b1 = (const float*)d_in[11];
  const float* eh_w2 = (const float*)d_in[12];
  const float* eh_b2 = (const float*)d_in[13];

  float* out_scores = (float*)d_out;
  float* out_mean = out_scores + N_EDGES;
  float* out_h = out_mean + 1;

  float* ws = (float*)d_ws;
  float* h0 = ws;                                   // 6.4M f32
  float* h1 = h0 + N_NODES * HID;                   // 6.4M f32
  float* agg = h1 + N_NODES * HID;                  // 6.4M f32
  unsigned long long* tbuf = (unsigned long long*)(agg + N_NODES * HID);  // 1.6M x 8B
  int* csr = (int*)(tbuf + N_EDGES);                // 1.6M int
  int* deg = csr + N_EDGES;                         // 100K int
  int* off = deg + N_NODES;                         // 100K+1 int
  int* bsum = off + N_NODES + 1;                    // NCHUNK
  int* bpre = bsum + NCHUNK;                        // NCHUNK
  int* bcur = bpre + NCHUNK;                        // NBUCK
  unsigned short* h0bf = (unsigned short*)(bcur + NBUCK + 3);  // 6.4M bf16
  unsigned short* h1bf = h0bf + (size_t)N_NODES * HID;         // 6.4M bf16
  unsigned short* w1p = h1bf + (size_t)N_NODES * HID;          // 8K bf16
  unsigned short* encwh = w1p + 8192;
  unsigned short* encwl = encwh + 8192;
  unsigned short* cw = encwl + 8192;
  unsigned short *lwhi0 = cw,         *lwlo0 = cw + 4096,  *rwhi0 = cw + 8192,  *rwlo0 = cw + 12288;
  unsigned short *lwhi1 = cw + 16384, *lwlo1 = cw + 20480, *rwhi1 = cw + 24576, *rwlo1 = cw + 28672;

  hipMemsetAsync(deg, 0, N_NODES * sizeof(int), stream);

  // weight packing (tiny)
  k_pack_hilo<<<(NODE_DIM * HID + 255) / 256, 256, 0, stream>>>(enc_w, encwh, encwl, NODE_DIM);
  k_pack_hilo<<<(HID * HID + 255) / 256, 256, 0, stream>>>(conv_lw, lwhi0, lwlo0, HID);
  k_pack_hilo<<<(HID * HID + 255) / 256, 256, 0, stream>>>(conv_rw, rwhi0, rwlo0, HID);
  k_pack_hilo<<<(HID * HID + 255) / 256, 256, 0, stream>>>(conv_lw + HID * HID, lwhi1, lwlo1, HID);
  k_pack_hilo<<<(HID * HID + 255) / 256, 256, 0, stream>>>(conv_rw + HID * HID, rwhi1, rwlo1, HID);
  k_pack_w1<<<(2 * HID * HID + 255) / 256, 256, 0, stream>>>(eh_w1, w1p);

  // CSR build (bucketed)
  k_deg<<<2048, 256, 0, stream>>>(dst, deg);
  k_scan_partial<<<NCHUNK, 1024, 0, stream>>>(deg, off, bsum);
  k_scan_bsums<<<1, 64, 0, stream>>>(bsum, bpre, off);
  k_scan_final<<<(N_NODES + 255) / 256, 256, 0, stream>>>(deg, bpre, off);
  k_init_bcur<<<(NBUCK + 255) / 256, 256, 0, stream>>>(off, bcur);
  k_partition<<<(N_EDGES + EPB_A - 1) / EPB_A, 256, 0, stream>>>(src, dst, bcur, tbuf);
  k_bucket<<<NBUCK, 512, 0, stream>>>(off, tbuf, csr);

  // encoder
  k_encode_mfma<<<1024, 256, 0, stream>>>(x, (const bf16x8*)encwh, (const bf16x8*)encwl, enc_b,
                                          h0, h0bf);

  // layer 0: h0 -> h1
  k_agg_bf<<<2048, 256, 0, stream>>>(off, csr, h0bf, agg);
  k_update_mfma<<<1024, 256, 0, stream>>>(agg, h0, (const bf16x8*)lwhi0, (const bf16x8*)lwlo0,
                                          conv_lb, (const bf16x8*)rwhi0, (const bf16x8*)rwlo0,
                                          h1, h1bf);

  // layer 1: h1 -> out_h (+ bf16 twin reusing h0bf)
  k_agg_bf<<<2048, 256, 0, stream>>>(off, csr, h1bf, agg);
  k_update_mfma<<<1024, 256, 0, stream>>>(agg, h1, (const bf16x8*)lwhi1, (const bf16x8*)lwlo1,
                                          conv_lb + HID, (const bf16x8*)rwhi1, (const bf16x8*)rwlo1,
                                          out_h, h0bf);

  // edge head + mean
  k_edge_head<<<2048, 256, 0, stream>>>(src, dst, h0bf, (const bf16x8*)w1p, eh_b1, eh_w2,
                                        eh_b2, out_scores);
  hipMemsetAsync(out_mean, 0, sizeof(float), stream);
  k_mean<<<2048, 256, 0, stream>>>(out_scores, out_mean);
}

// Round 4
// 343.696 us; speedup vs baseline: 4.5051x; 1.4746x over previous
//
#include <hip/hip_runtime.h>
#include <hip/hip_bf16.h>

#define N_NODES 100000
#define N_EDGES 1600000
#define HID 64
#define NODE_DIM 128
#define NPB 512                              // nodes per bucket (dst>>9)
#define NBUCK ((N_NODES + NPB - 1) / NPB)    // 196
#define EPB_A 4096                           // edges per partition block

typedef __attribute__((ext_vector_type(8))) short bf16x8;
typedef __attribute__((ext_vector_type(8))) float f32x8;
typedef __attribute__((ext_vector_type(4))) float f32x4;

__device__ __forceinline__ unsigned short f2bf(float f) {
  __hip_bfloat16 h = __float2bfloat16(f);
  return *reinterpret_cast<unsigned short*>(&h);
}
__device__ __forceinline__ float bf2f(unsigned short u) {
  __hip_bfloat16 h = *reinterpret_cast<__hip_bfloat16*>(&u);
  return __bfloat162float(h);
}

// pack one element of W[K][64] into MFMA B-frag order, hi/lo bf16 split
__device__ __forceinline__ void pack_one(const float* __restrict__ w,
                                         unsigned short* __restrict__ whi,
                                         unsigned short* __restrict__ wlo, int i) {
  int j = i & 7, lane = (i >> 3) & 63, ct = (i >> 9) & 3, kt = i >> 11;
  int k = kt * 32 + (lane >> 4) * 8 + j;
  int c = ct * 16 + (lane & 15);
  float v = w[k * HID + c];
  unsigned short hi = f2bf(v);
  whi[i] = hi;
  wlo[i] = f2bf(v - bf2f(hi));
}

// ---- all weight packing + per-call zeroing, one launch (grid 32x256) ----
__global__ void k_pack_all(const float* __restrict__ enc_w, const float* __restrict__ conv_lw,
                           const float* __restrict__ conv_rw, const float* __restrict__ eh_w1,
                           unsigned short* __restrict__ encwh, unsigned short* __restrict__ encwl,
                           unsigned short* __restrict__ cw, unsigned short* __restrict__ w1p,
                           unsigned short* __restrict__ w1lo, int* __restrict__ bcnt,
                           float* __restrict__ out_mean) {
  int i = blockIdx.x * blockDim.x + threadIdx.x;
  if (i < NODE_DIM * HID) pack_one(enc_w, encwh, encwl, i);
  if (i < HID * HID) {
    pack_one(conv_lw, cw + 0 * 4096, cw + 1 * 4096, i);
    pack_one(conv_rw, cw + 2 * 4096, cw + 3 * 4096, i);
    pack_one(conv_lw + HID * HID, cw + 4 * 4096, cw + 5 * 4096, i);
    pack_one(conv_rw + HID * HID, cw + 6 * 4096, cw + 7 * 4096, i);
  }
  if (i < 2 * HID * HID) pack_one(eh_w1, w1p, w1lo, i);
  if (i < NBUCK) bcnt[i] = 0;
  if (i == 0) *out_mean = 0.f;
}

// ---- bucket-level histogram (196 counters) ----
__global__ void k_bhist(const int* __restrict__ dst, int* __restrict__ bcnt) {
  __shared__ int h[NBUCK];
  for (int i = threadIdx.x; i < NBUCK; i += blockDim.x) h[i] = 0;
  __syncthreads();
  int stride = gridDim.x * blockDim.x;
  for (int e = blockIdx.x * blockDim.x + threadIdx.x; e < N_EDGES; e += stride)
    atomicAdd(&h[dst[e] >> 9], 1);
  __syncthreads();
  for (int i = threadIdx.x; i < NBUCK; i += blockDim.x)
    if (h[i]) atomicAdd(&bcnt[i], h[i]);
}

// ---- tiny serial scan of 196 bucket counts ----
__global__ void k_bscan(const int* __restrict__ bcnt, int* __restrict__ bbase,
                        int* __restrict__ bcur, int* __restrict__ off) {
  if (threadIdx.x == 0 && blockIdx.x == 0) {
    int run = 0;
    for (int b = 0; b < NBUCK; ++b) {
      bbase[b] = run;
      bcur[b] = run;
      run += bcnt[b];
    }
    bbase[NBUCK] = run;
    off[N_NODES] = run;  // == N_EDGES
  }
}

// ---- phase A: partition edges into dst-buckets (ranked contiguous writes) ----
__global__ void k_partition(const int* __restrict__ src, const int* __restrict__ dst,
                            int* __restrict__ bcur, unsigned long long* __restrict__ tbuf) {
  __shared__ int hist[NBUCK];
  for (int i = threadIdx.x; i < NBUCK; i += blockDim.x) hist[i] = 0;
  __syncthreads();
  int e0 = blockIdx.x * EPB_A;
#pragma unroll
  for (int k = 0; k < EPB_A / 256; ++k) {
    int e = e0 + k * 256 + threadIdx.x;
    if (e < N_EDGES) atomicAdd(&hist[dst[e] >> 9], 1);
  }
  __syncthreads();
  for (int b = threadIdx.x; b < NBUCK; b += blockDim.x) {
    int c = hist[b];
    hist[b] = c ? atomicAdd(&bcur[b], c) : 0;
  }
  __syncthreads();
#pragma unroll
  for (int k = 0; k < EPB_A / 256; ++k) {
    int e = e0 + k * 256 + threadIdx.x;
    if (e < N_EDGES) {
      int s = src[e], d = dst[e];
      int pos = atomicAdd(&hist[d >> 9], 1);
      tbuf[pos] = (unsigned long long)(unsigned)s | ((unsigned long long)(unsigned)d << 32);
    }
  }
}

// ---- phase B: per-bucket node offsets (LDS hist+scan) + CSR rank fill ----
__global__ void k_bucket2(const int* __restrict__ bbase,
                          const unsigned long long* __restrict__ tbuf,
                          int* __restrict__ csr, int* __restrict__ off) {
  __shared__ int cnt[NPB];
  __shared__ int wsum[8];
  const int b = blockIdx.x;
  const int n0 = b * NPB;
  const int nn = min(NPB, N_NODES - n0);
  const int t0 = bbase[b], t1 = bbase[b + 1];
  cnt[threadIdx.x] = 0;  // blockDim == NPB == 512
  __syncthreads();
  for (int t = t0 + threadIdx.x; t < t1; t += blockDim.x)
    atomicAdd(&cnt[(int)(tbuf[t] >> 32) - n0], 1);
  __syncthreads();
  // block exclusive scan over 512 counts
  int v = (threadIdx.x < nn) ? cnt[threadIdx.x] : 0;
  int lane = threadIdx.x & 63, wid = threadIdx.x >> 6;
  int s = v;
#pragma unroll
  for (int d = 1; d < 64; d <<= 1) {
    int t = __shfl_up(s, d);
    if (lane >= d) s += t;
  }
  if (lane == 63) wsum[wid] = s;
  __syncthreads();
  if (wid == 0 && lane < 8) {
    int t = wsum[lane];
#pragma unroll
    for (int d = 1; d < 8; d <<= 1) {
      int u = __shfl_up(t, d);
      if (lane >= d) t += u;
    }
    wsum[lane] = t;
  }
  __syncthreads();
  int cur0 = t0 + (s - v) + (wid > 0 ? wsum[wid - 1] : 0);
  __syncthreads();  // all reads of cnt done before overwrite
  if (threadIdx.x < nn) {
    off[n0 + threadIdx.x] = cur0;
    cnt[threadIdx.x] = cur0;
  }
  __syncthreads();
  for (int t = t0 + threadIdx.x; t < t1; t += blockDim.x) {
    unsigned long long u = tbuf[t];
    int s2 = (int)(u & 0xffffffffULL);
    int d2 = (int)(u >> 32) - n0;
    int pos = atomicAdd(&cnt[d2], 1);
    csr[pos] = s2;
  }
}

// ---- encoder: h = relu(x @ W + b) via MFMA; writes f32 h + bf16 twin ----
__global__ void k_encode_mfma(const float* __restrict__ x, const bf16x8* __restrict__ whi,
                              const bf16x8* __restrict__ wlo, const float* __restrict__ b,
                              float* __restrict__ h, unsigned short* __restrict__ hbf) {
  const int lane = threadIdx.x & 63;
  const int er = lane & 15, kb = lane >> 4;
  int gw = (blockIdx.x * blockDim.x + threadIdx.x) >> 6;
  int nw = (gridDim.x * blockDim.x) >> 6;
  const int ntiles = N_NODES / 16;
  for (int tile = gw; tile < ntiles; tile += nw) {
    int R = tile * 16;
    f32x4 acc[4] = {{0.f, 0.f, 0.f, 0.f}, {0.f, 0.f, 0.f, 0.f}, {0.f, 0.f, 0.f, 0.f}, {0.f, 0.f, 0.f, 0.f}};
#pragma unroll
    for (int kt = 0; kt < 4; ++kt) {
      f32x8 xv = *reinterpret_cast<const f32x8*>(x + (size_t)(R + er) * NODE_DIM + kt * 32 + kb * 8);
      bf16x8 ahi, alo;
#pragma unroll
      for (int j = 0; j < 8; ++j) {
        unsigned short hi = f2bf(xv[j]);
        ahi[j] = (short)hi;
        alo[j] = (short)f2bf(xv[j] - bf2f(hi));
      }
#pragma unroll
      for (int ct = 0; ct < 4; ++ct) {
        bf16x8 bh = whi[(kt * 4 + ct) * 64 + lane];
        bf16x8 bl = wlo[(kt * 4 + ct) * 64 + lane];
        acc[ct] = __builtin_amdgcn_mfma_f32_16x16x32_bf16(ahi, bh, acc[ct], 0, 0, 0);
        acc[ct] = __builtin_amdgcn_mfma_f32_16x16x32_bf16(alo, bh, acc[ct], 0, 0, 0);
        acc[ct] = __builtin_amdgcn_mfma_f32_16x16x32_bf16(ahi, bl, acc[ct], 0, 0, 0);
      }
    }
#pragma unroll
    for (int ct = 0; ct < 4; ++ct) {
      float bb = b[ct * 16 + er];
#pragma unroll
      for (int r = 0; r < 4; ++r) {
        float v = fmaxf(acc[ct][r] + bb, 0.f);
        size_t idx = (size_t)(R + kb * 4 + r) * HID + ct * 16 + er;
        h[idx] = v;
        hbf[idx] = f2bf(v);
      }
    }
  }
}

// ---- fused SAGE layer: register-resident mean-agg (row-parallel gather,
//      lands in A-frag layout) + MFMA update. One wave per 16-node tile. ----
__global__ void k_layer(const int* __restrict__ off, const int* __restrict__ csr,
                        const unsigned short* __restrict__ hbf_in,
                        const float* __restrict__ h_in,
                        const bf16x8* __restrict__ lwhi, const bf16x8* __restrict__ lwlo,
                        const float* __restrict__ lb,
                        const bf16x8* __restrict__ rwhi, const bf16x8* __restrict__ rwlo,
                        float* __restrict__ hout, unsigned short* __restrict__ hbf_out) {
  const int lane = threadIdx.x & 63;
  const int er = lane & 15, kb = lane >> 4;
  const int gw = (blockIdx.x * blockDim.x + threadIdx.x) >> 6;
  const int ntiles = N_NODES / 16;  // 6250
  if (gw >= ntiles) return;
  const int R = gw * 16;
  const int n = R + er;
  const int s0 = off[n], s1 = off[n + 1];

  // gather-mean for node row `er`, features kb*8..+8 and 32+kb*8..+8
  float a[16];
#pragma unroll
  for (int j = 0; j < 16; ++j) a[j] = 0.f;
  int it = s0;
  for (; it + 2 <= s1; it += 2) {
    int i0 = csr[it], i1 = csr[it + 1];
    bf16x8 u0 = *reinterpret_cast<const bf16x8*>(hbf_in + (size_t)i0 * HID + kb * 8);
    bf16x8 u1 = *reinterpret_cast<const bf16x8*>(hbf_in + (size_t)i0 * HID + 32 + kb * 8);
    bf16x8 v0 = *reinterpret_cast<const bf16x8*>(hbf_in + (size_t)i1 * HID + kb * 8);
    bf16x8 v1 = *reinterpret_cast<const bf16x8*>(hbf_in + (size_t)i1 * HID + 32 + kb * 8);
#pragma unroll
    for (int j = 0; j < 8; ++j) {
      a[j] += bf2f((unsigned short)u0[j]) + bf2f((unsigned short)v0[j]);
      a[8 + j] += bf2f((unsigned short)u1[j]) + bf2f((unsigned short)v1[j]);
    }
  }
  if (it < s1) {
    int i0 = csr[it];
    bf16x8 u0 = *reinterpret_cast<const bf16x8*>(hbf_in + (size_t)i0 * HID + kb * 8);
    bf16x8 u1 = *reinterpret_cast<const bf16x8*>(hbf_in + (size_t)i0 * HID + 32 + kb * 8);
#pragma unroll
    for (int j = 0; j < 8; ++j) {
      a[j] += bf2f((unsigned short)u0[j]);
      a[8 + j] += bf2f((unsigned short)u1[j]);
    }
  }
  const float ic = (s1 > s0) ? 1.f / (float)(s1 - s0) : 0.f;

  // build A-fragments (agg hi/lo, h hi/lo)
  bf16x8 ahi[2], alo[2], hhi[2], hlo[2];
#pragma unroll
  for (int kt = 0; kt < 2; ++kt) {
    f32x8 hv = *reinterpret_cast<const f32x8*>(h_in + (size_t)n * HID + kt * 32 + kb * 8);
#pragma unroll
    for (int j = 0; j < 8; ++j) {
      float av = a[kt * 8 + j] * ic;
      unsigned short u = f2bf(av);
      ahi[kt][j] = (short)u;
      alo[kt][j] = (short)f2bf(av - bf2f(u));
      unsigned short w = f2bf(hv[j]);
      hhi[kt][j] = (short)w;
      hlo[kt][j] = (short)f2bf(hv[j] - bf2f(w));
    }
  }

  f32x4 acc[4] = {{0.f, 0.f, 0.f, 0.f}, {0.f, 0.f, 0.f, 0.f}, {0.f, 0.f, 0.f, 0.f}, {0.f, 0.f, 0.f, 0.f}};
#pragma unroll
  for (int kt = 0; kt < 2; ++kt) {
#pragma unroll
    for (int ct = 0; ct < 4; ++ct) {
      bf16x8 lh = lwhi[(kt * 4 + ct) * 64 + lane];
      bf16x8 ll = lwlo[(kt * 4 + ct) * 64 + lane];
      bf16x8 rh = rwhi[(kt * 4 + ct) * 64 + lane];
      bf16x8 rl = rwlo[(kt * 4 + ct) * 64 + lane];
      acc[ct] = __builtin_amdgcn_mfma_f32_16x16x32_bf16(ahi[kt], lh, acc[ct], 0, 0, 0);
      acc[ct] = __builtin_amdgcn_mfma_f32_16x16x32_bf16(alo[kt], lh, acc[ct], 0, 0, 0);
      acc[ct] = __builtin_amdgcn_mfma_f32_16x16x32_bf16(ahi[kt], ll, acc[ct], 0, 0, 0);
      acc[ct] = __builtin_amdgcn_mfma_f32_16x16x32_bf16(hhi[kt], rh, acc[ct], 0, 0, 0);
      acc[ct] = __builtin_amdgcn_mfma_f32_16x16x32_bf16(hlo[kt], rh, acc[ct], 0, 0, 0);
      acc[ct] = __builtin_amdgcn_mfma_f32_16x16x32_bf16(hhi[kt], rl, acc[ct], 0, 0, 0);
    }
  }
#pragma unroll
  for (int ct = 0; ct < 4; ++ct) {
    float bb = lb[ct * 16 + er];
#pragma unroll
    for (int r = 0; r < 4; ++r) {
      float v = fmaxf(acc[ct][r] + bb, 0.f);
      size_t idx = (size_t)(R + kb * 4 + r) * HID + ct * 16 + er;
      hout[idx] = v;
      hbf_out[idx] = f2bf(v);
    }
  }
}

// ---- edge head + fused mean: wave per 16 edges, bf16 MFMA ----
__global__ void k_edge_head(const int* __restrict__ src, const int* __restrict__ dst,
                            const unsigned short* __restrict__ hbf,
                            const bf16x8* __restrict__ w1p,
                            const float* __restrict__ b1, const float* __restrict__ w2,
                            const float* __restrict__ b2, float* __restrict__ scores,
                            float* __restrict__ out_mean) {
  const int lane = threadIdx.x & 63;
  const int wid = threadIdx.x >> 6;
  const int wpb = blockDim.x >> 6;
  const int nw = gridDim.x * wpb;
  const int er = lane & 15;
  const int kb = lane >> 4;
  const int ntiles = N_EDGES / 16;
  float b1c[4], w2c[4];
#pragma unroll
  for (int f = 0; f < 4; ++f) {
    b1c[f] = b1[f * 16 + er];
    w2c[f] = w2[f * 16 + er];
  }
  const float bb = b2[0];
  float msum = 0.f;
  for (int tile = blockIdx.x * wpb + wid; tile < ntiles; tile += nw) {
    int e = tile * 16 + er;
    int s = src[e], d = dst[e];
    f32x4 acc0 = {0.f, 0.f, 0.f, 0.f}, acc1 = acc0, acc2 = acc0, acc3 = acc0;
#pragma unroll
    for (int kt = 0; kt < 4; ++kt) {
      int row = (kt < 2) ? s : d;
      int koff = (kt & 1) * 32;
      bf16x8 a = *reinterpret_cast<const bf16x8*>(hbf + (size_t)row * HID + koff + kb * 8);
      acc0 = __builtin_amdgcn_mfma_f32_16x16x32_bf16(a, w1p[(kt * 4 + 0) * 64 + lane], acc0, 0, 0, 0);
      acc1 = __builtin_amdgcn_mfma_f32_16x16x32_bf16(a, w1p[(kt * 4 + 1) * 64 + lane], acc1, 0, 0, 0);
      acc2 = __builtin_amdgcn_mfma_f32_16x16x32_bf16(a, w1p[(kt * 4 + 2) * 64 + lane], acc2, 0, 0, 0);
      acc3 = __builtin_amdgcn_mfma_f32_16x16x32_bf16(a, w1p[(kt * 4 + 3) * 64 + lane], acc3, 0, 0, 0);
    }
    float part[4] = {0.f, 0.f, 0.f, 0.f};
#define EPI(ACC, F)                                       \
  {                                                       \
    part[0] += fmaxf(ACC[0] + b1c[F], 0.f) * w2c[F];      \
    part[1] += fmaxf(ACC[1] + b1c[F], 0.f) * w2c[F];      \
    part[2] += fmaxf(ACC[2] + b1c[F], 0.f) * w2c[F];      \
    part[3] += fmaxf(ACC[3] + b1c[F], 0.f) * w2c[F];      \
  }
    EPI(acc0, 0) EPI(acc1, 1) EPI(acc2, 2) EPI(acc3, 3)
#undef EPI
#pragma unroll
    for (int off = 1; off < 16; off <<= 1) {
      part[0] += __shfl_xor(part[0], off);
      part[1] += __shfl_xor(part[1], off);
      part[2] += __shfl_xor(part[2], off);
      part[3] += __shfl_xor(part[3], off);
    }
    if (er == 0) {
#pragma unroll
      for (int r = 0; r < 4; ++r) {
        int eo = tile * 16 + kb * 4 + r;
        float sc = 1.f / (1.f + __expf(-(part[r] + bb)));
        scores[eo] = sc;
        msum += sc;
      }
    }
  }
  // block-level mean reduction (uniform post-loop barrier)
#pragma unroll
  for (int o = 1; o < 64; o <<= 1) msum += __shfl_xor(msum, o);
  __shared__ float bs[8];
  if (lane == 0) bs[wid] = msum;
  __syncthreads();
  if (threadIdx.x == 0) {
    float t = 0.f;
    for (int i = 0; i < wpb; ++i) t += bs[i];
    atomicAdd(out_mean, t * (1.f / (float)N_EDGES));
  }
}

extern "C" void kernel_launch(void* const* d_in, const int* in_sizes, int n_in,
                              void* d_out, int out_size, void* d_ws, size_t ws_size,
                              hipStream_t stream) {
  const float* x = (const float*)d_in[0];
  const int* ei = (const int*)d_in[1];
  const int* src = ei;
  const int* dst = ei + N_EDGES;
  const float* enc_w = (const float*)d_in[3];
  const float* enc_b = (const float*)d_in[4];
  const float* conv_lw = (const float*)d_in[7];
  const float* conv_lb = (const float*)d_in[8];
  const float* conv_rw = (const float*)d_in[9];
  const float* eh_w1 = (const float*)d_in[10];
  const float* eh_b1 = (const float*)d_in[11];
  const float* eh_w2 = (const float*)d_in[12];
  const float* eh_b2 = (const float*)d_in[13];

  float* out_scores = (float*)d_out;
  float* out_mean = out_scores + N_EDGES;
  float* out_h = out_mean + 1;

  float* ws = (float*)d_ws;
  float* h0 = ws;                                                        // 6.4M f32
  float* h1 = h0 + (size_t)N_NODES * HID;                                // 6.4M f32
  unsigned long long* tbuf = (unsigned long long*)(h1 + (size_t)N_NODES * HID);  // 1.6M x 8B
  int* csr = (int*)(tbuf + N_EDGES);                                     // 1.6M int
  int* off = csr + N_EDGES;                                              // 100K+1 int
  int* bcnt = off + N_NODES + 1;                                         // NBUCK
  int* bbase = bcnt + NBUCK;                                             // NBUCK+1
  int* bcur = bbase + NBUCK + 1;                                         // NBUCK
  unsigned short* h0bf = (unsigned short*)(bcur + NBUCK + 2);            // 6.4M bf16
  unsigned short* h1bf = h0bf + (size_t)N_NODES * HID;                   // 6.4M bf16
  unsigned short* w1p = h1bf + (size_t)N_NODES * HID;                    // 8K
  unsigned short* w1lo = w1p + 8192;                                     // 8K (unused)
  unsigned short* encwh = w1lo + 8192;                                   // 8K
  unsigned short* encwl = encwh + 8192;                                  // 8K
  unsigned short* cw = encwl + 8192;                                     // 8 x 4096
  const bf16x8 *lwhi0 = (const bf16x8*)(cw + 0 * 4096), *lwlo0 = (const bf16x8*)(cw + 1 * 4096);
  const bf16x8 *rwhi0 = (const bf16x8*)(cw + 2 * 4096), *rwlo0 = (const bf16x8*)(cw + 3 * 4096);
  const bf16x8 *lwhi1 = (const bf16x8*)(cw + 4 * 4096), *lwlo1 = (const bf16x8*)(cw + 5 * 4096);
  const bf16x8 *rwhi1 = (const bf16x8*)(cw + 6 * 4096), *rwlo1 = (const bf16x8*)(cw + 7 * 4096);

  // 1. packs + zeroing
  k_pack_all<<<32, 256, 0, stream>>>(enc_w, conv_lw, conv_rw, eh_w1, encwh, encwl, cw,
                                     w1p, w1lo, bcnt, out_mean);
  // 2-5. CSR build (bucketed, no node-level scan chain)
  k_bhist<<<512, 256, 0, stream>>>(dst, bcnt);
  k_bscan<<<1, 64, 0, stream>>>(bcnt, bbase, bcur, off);
  k_partition<<<(N_EDGES + EPB_A - 1) / EPB_A, 256, 0, stream>>>(src, dst, bcur, tbuf);
  k_bucket2<<<NBUCK, NPB, 0, stream>>>(bbase, tbuf, csr, off);
  // 6. encoder
  k_encode_mfma<<<1024, 256, 0, stream>>>(x, (const bf16x8*)encwh, (const bf16x8*)encwl,
                                          enc_b, h0, h0bf);
  // 7-8. fused SAGE layers
  const int LGRID = (N_NODES / 16 + 3) / 4;  // 4 waves/block
  k_layer<<<LGRID, 256, 0, stream>>>(off, csr, h0bf, h0, lwhi0, lwlo0, conv_lb,
                                     rwhi0, rwlo0, h1, h1bf);
  k_layer<<<LGRID, 256, 0, stream>>>(off, csr, h1bf, h1, lwhi1, lwlo1, conv_lb + HID,
                                     rwhi1, rwlo1, out_h, h0bf);
  // 9. edge head + mean
  k_edge_head<<<2048, 256, 0, stream>>>(src, dst, h0bf, (const bf16x8*)w1p, eh_b1, eh_w2,
                                        eh_b2, out_scores, out_mean);
}

// Round 5
// 319.435 us; speedup vs baseline: 4.8472x; 1.0759x over previous
//
#include <hip/hip_runtime.h>
#include <hip/hip_bf16.h>

#define N_NODES 100000
#define N_EDGES 1600000
#define HID 64
#define NODE_DIM 128
#define NPB 512                              // nodes per bucket (dst>>9)
#define NBUCK ((N_NODES + NPB - 1) / NPB)    // 196
#define EPB_A 4096                           // edges per partition block
#define NTILES (N_NODES / 16)                // 6250

typedef __attribute__((ext_vector_type(8))) short bf16x8;
typedef __attribute__((ext_vector_type(8))) float f32x8;
typedef __attribute__((ext_vector_type(4))) float f32x4;
typedef __attribute__((ext_vector_type(2))) float f32x2;
typedef __attribute__((ext_vector_type(4))) unsigned int u32x4;

__device__ __forceinline__ unsigned short f2bf(float f) {
  __hip_bfloat16 h = __float2bfloat16(f);
  return *reinterpret_cast<unsigned short*>(&h);
}
__device__ __forceinline__ float bf2f(unsigned short u) {
  __hip_bfloat16 h = *reinterpret_cast<__hip_bfloat16*>(&u);
  return __bfloat162float(h);
}

// pack one element of W[K][64] into MFMA B-frag order, hi/lo bf16 split
__device__ __forceinline__ void pack_one(const float* __restrict__ w,
                                         unsigned short* __restrict__ whi,
                                         unsigned short* __restrict__ wlo, int i) {
  int j = i & 7, lane = (i >> 3) & 63, ct = (i >> 9) & 3, kt = i >> 11;
  int k = kt * 32 + (lane >> 4) * 8 + j;
  int c = ct * 16 + (lane & 15);
  float v = w[k * HID + c];
  unsigned short hi = f2bf(v);
  whi[i] = hi;
  wlo[i] = f2bf(v - bf2f(hi));
}
__device__ __forceinline__ void pack_one_hi(const float* __restrict__ w,
                                            unsigned short* __restrict__ whi, int i) {
  int j = i & 7, lane = (i >> 3) & 63, ct = (i >> 9) & 3, kt = i >> 11;
  int k = kt * 32 + (lane >> 4) * 8 + j;
  int c = ct * 16 + (lane & 15);
  whi[i] = f2bf(w[k * HID + c]);
}

// ---- all weight packing + per-call zeroing, one launch (grid 32x256) ----
__global__ void k_pack_all(const float* __restrict__ enc_w, const float* __restrict__ conv_lw,
                           const float* __restrict__ conv_rw, const float* __restrict__ eh_w1,
                           unsigned short* __restrict__ encwh, unsigned short* __restrict__ encwl,
                           unsigned short* __restrict__ cw, unsigned short* __restrict__ w1s,
                           unsigned short* __restrict__ w1d, int* __restrict__ bcnt,
                           float* __restrict__ out_mean) {
  int i = blockIdx.x * blockDim.x + threadIdx.x;
  if (i < NODE_DIM * HID) pack_one(enc_w, encwh, encwl, i);
  if (i < HID * HID) {
    pack_one(conv_lw, cw + 0 * 4096, cw + 1 * 4096, i);
    pack_one(conv_rw, cw + 2 * 4096, cw + 3 * 4096, i);
    pack_one(conv_lw + HID * HID, cw + 4 * 4096, cw + 5 * 4096, i);
    pack_one(conv_rw + HID * HID, cw + 6 * 4096, cw + 7 * 4096, i);
  }
  if (i < HID * HID) {
    pack_one_hi(eh_w1, w1s, i);                  // W1[0:64][:]
    pack_one_hi(eh_w1 + HID * HID, w1d, i);      // W1[64:128][:]
  }
  if (i < NBUCK) bcnt[i] = 0;
  if (i == 0) *out_mean = 0.f;
}

// ---- bucket-level histogram (196 counters) ----
__global__ void k_bhist(const int* __restrict__ dst, int* __restrict__ bcnt) {
  __shared__ int h[NBUCK];
  for (int i = threadIdx.x; i < NBUCK; i += blockDim.x) h[i] = 0;
  __syncthreads();
  int stride = gridDim.x * blockDim.x;
  for (int e = blockIdx.x * blockDim.x + threadIdx.x; e < N_EDGES; e += stride)
    atomicAdd(&h[dst[e] >> 9], 1);
  __syncthreads();
  for (int i = threadIdx.x; i < NBUCK; i += blockDim.x)
    if (h[i]) atomicAdd(&bcnt[i], h[i]);
}

// ---- tiny serial scan of 196 bucket counts ----
__global__ void k_bscan(const int* __restrict__ bcnt, int* __restrict__ bbase,
                        int* __restrict__ bcur, int* __restrict__ off) {
  if (threadIdx.x == 0 && blockIdx.x == 0) {
    int run = 0;
    for (int b = 0; b < NBUCK; ++b) {
      bbase[b] = run;
      bcur[b] = run;
      run += bcnt[b];
    }
    bbase[NBUCK] = run;
    off[N_NODES] = run;  // == N_EDGES
  }
}

// ---- phase A: partition edges into dst-buckets; 4B entries (src|dl<<17) ----
__global__ void k_partition(const int* __restrict__ src, const int* __restrict__ dst,
                            int* __restrict__ bcur, unsigned int* __restrict__ tbuf) {
  __shared__ int hist[NBUCK];
  for (int i = threadIdx.x; i < NBUCK; i += blockDim.x) hist[i] = 0;
  __syncthreads();
  int e0 = blockIdx.x * EPB_A;
#pragma unroll
  for (int k = 0; k < EPB_A / 256; ++k) {
    int e = e0 + k * 256 + threadIdx.x;
    if (e < N_EDGES) atomicAdd(&hist[dst[e] >> 9], 1);
  }
  __syncthreads();
  for (int b = threadIdx.x; b < NBUCK; b += blockDim.x) {
    int c = hist[b];
    hist[b] = c ? atomicAdd(&bcur[b], c) : 0;
  }
  __syncthreads();
#pragma unroll
  for (int k = 0; k < EPB_A / 256; ++k) {
    int e = e0 + k * 256 + threadIdx.x;
    if (e < N_EDGES) {
      int s = src[e], d = dst[e];
      int pos = atomicAdd(&hist[d >> 9], 1);
      tbuf[pos] = (unsigned)s | ((unsigned)(d & (NPB - 1)) << 17);
    }
  }
}

// ---- phase B: per-bucket node offsets (LDS hist+scan) + CSR rank fill ----
__global__ void k_bucket2(const int* __restrict__ bbase, const unsigned int* __restrict__ tbuf,
                          int* __restrict__ csr, int* __restrict__ off) {
  __shared__ int cnt[NPB];
  __shared__ int wsum[8];
  const int b = blockIdx.x;
  const int n0 = b * NPB;
  const int nn = min(NPB, N_NODES - n0);
  const int t0 = bbase[b], t1 = bbase[b + 1];
  cnt[threadIdx.x] = 0;  // blockDim == NPB == 512
  __syncthreads();
  for (int t = t0 + threadIdx.x; t < t1; t += blockDim.x)
    atomicAdd(&cnt[tbuf[t] >> 17], 1);
  __syncthreads();
  int v = (threadIdx.x < nn) ? cnt[threadIdx.x] : 0;
  int lane = threadIdx.x & 63, wid = threadIdx.x >> 6;
  int s = v;
#pragma unroll
  for (int d = 1; d < 64; d <<= 1) {
    int t = __shfl_up(s, d);
    if (lane >= d) s += t;
  }
  if (lane == 63) wsum[wid] = s;
  __syncthreads();
  if (wid == 0 && lane < 8) {
    int t = wsum[lane];
#pragma unroll
    for (int d = 1; d < 8; d <<= 1) {
      int u = __shfl_up(t, d);
      if (lane >= d) t += u;
    }
    wsum[lane] = t;
  }
  __syncthreads();
  int cur0 = t0 + (s - v) + (wid > 0 ? wsum[wid - 1] : 0);
  __syncthreads();
  if (threadIdx.x < nn) {
    off[n0 + threadIdx.x] = cur0;
    cnt[threadIdx.x] = cur0;
  }
  __syncthreads();
  for (int t = t0 + threadIdx.x; t < t1; t += blockDim.x) {
    unsigned int u = tbuf[t];
    int pos = atomicAdd(&cnt[u >> 17], 1);
    csr[pos] = (int)(u & 0x1FFFFu);
  }
}

// ---- encoder: h = relu(x @ W + b) via MFMA; writes bf16 h only ----
__global__ void k_encode_mfma(const float* __restrict__ x, const bf16x8* __restrict__ whi,
                              const bf16x8* __restrict__ wlo, const float* __restrict__ b,
                              unsigned short* __restrict__ hbf) {
  const int lane = threadIdx.x & 63;
  const int er = lane & 15, kb = lane >> 4;
  int gw = (blockIdx.x * blockDim.x + threadIdx.x) >> 6;
  int nw = (gridDim.x * blockDim.x) >> 6;
  for (int tile = gw; tile < NTILES; tile += nw) {
    int R = tile * 16;
    f32x4 acc[4] = {{0.f, 0.f, 0.f, 0.f}, {0.f, 0.f, 0.f, 0.f}, {0.f, 0.f, 0.f, 0.f}, {0.f, 0.f, 0.f, 0.f}};
#pragma unroll
    for (int kt = 0; kt < 4; ++kt) {
      f32x8 xv = *reinterpret_cast<const f32x8*>(x + (size_t)(R + er) * NODE_DIM + kt * 32 + kb * 8);
      bf16x8 ahi, alo;
#pragma unroll
      for (int j = 0; j < 8; ++j) {
        unsigned short hi = f2bf(xv[j]);
        ahi[j] = (short)hi;
        alo[j] = (short)f2bf(xv[j] - bf2f(hi));
      }
#pragma unroll
      for (int ct = 0; ct < 4; ++ct) {
        bf16x8 bh = whi[(kt * 4 + ct) * 64 + lane];
        bf16x8 bl = wlo[(kt * 4 + ct) * 64 + lane];
        acc[ct] = __builtin_amdgcn_mfma_f32_16x16x32_bf16(ahi, bh, acc[ct], 0, 0, 0);
        acc[ct] = __builtin_amdgcn_mfma_f32_16x16x32_bf16(alo, bh, acc[ct], 0, 0, 0);
        acc[ct] = __builtin_amdgcn_mfma_f32_16x16x32_bf16(ahi, bl, acc[ct], 0, 0, 0);
      }
    }
#pragma unroll
    for (int ct = 0; ct < 4; ++ct) {
      float bb = b[ct * 16 + er];
#pragma unroll
      for (int r = 0; r < 4; ++r)
        hbf[(size_t)(R + kb * 4 + r) * HID + ct * 16 + er] = f2bf(fmaxf(acc[ct][r] + bb, 0.f));
    }
  }
}

// ---- fused SAGE layer, bf16-only h: register mean-agg + MFMA update ----
__global__ void k_layer(const int* __restrict__ off, const int* __restrict__ csr,
                        const unsigned short* __restrict__ hbf_in,
                        const bf16x8* __restrict__ lwhi, const bf16x8* __restrict__ lwlo,
                        const float* __restrict__ lb,
                        const bf16x8* __restrict__ rwhi, const bf16x8* __restrict__ rwlo,
                        float* __restrict__ hout_f32, unsigned short* __restrict__ hbf_out) {
  const int lane = threadIdx.x & 63;
  const int er = lane & 15, kb = lane >> 4;
  const int gw = (blockIdx.x * blockDim.x + threadIdx.x) >> 6;
  if (gw >= NTILES) return;
  const int R = gw * 16;
  const int n = R + er;
  const int s0 = off[n], s1 = off[n + 1];

  float a[16];
#pragma unroll
  for (int j = 0; j < 16; ++j) a[j] = 0.f;
  int it = s0;
  for (; it + 2 <= s1; it += 2) {
    int i0 = csr[it], i1 = csr[it + 1];
    bf16x8 u0 = *reinterpret_cast<const bf16x8*>(hbf_in + (size_t)i0 * HID + kb * 8);
    bf16x8 u1 = *reinterpret_cast<const bf16x8*>(hbf_in + (size_t)i0 * HID + 32 + kb * 8);
    bf16x8 v0 = *reinterpret_cast<const bf16x8*>(hbf_in + (size_t)i1 * HID + kb * 8);
    bf16x8 v1 = *reinterpret_cast<const bf16x8*>(hbf_in + (size_t)i1 * HID + 32 + kb * 8);
#pragma unroll
    for (int j = 0; j < 8; ++j) {
      a[j] += bf2f((unsigned short)u0[j]) + bf2f((unsigned short)v0[j]);
      a[8 + j] += bf2f((unsigned short)u1[j]) + bf2f((unsigned short)v1[j]);
    }
  }
  if (it < s1) {
    int i0 = csr[it];
    bf16x8 u0 = *reinterpret_cast<const bf16x8*>(hbf_in + (size_t)i0 * HID + kb * 8);
    bf16x8 u1 = *reinterpret_cast<const bf16x8*>(hbf_in + (size_t)i0 * HID + 32 + kb * 8);
#pragma unroll
    for (int j = 0; j < 8; ++j) {
      a[j] += bf2f((unsigned short)u0[j]);
      a[8 + j] += bf2f((unsigned short)u1[j]);
    }
  }
  const float ic = (s1 > s0) ? 1.f / (float)(s1 - s0) : 0.f;

  // self A-frags (bf16 h directly) + agg hi/lo split
  bf16x8 hv[2], ahi[2], alo[2];
  hv[0] = *reinterpret_cast<const bf16x8*>(hbf_in + (size_t)n * HID + kb * 8);
  hv[1] = *reinterpret_cast<const bf16x8*>(hbf_in + (size_t)n * HID + 32 + kb * 8);
#pragma unroll
  for (int kt = 0; kt < 2; ++kt) {
#pragma unroll
    for (int j = 0; j < 8; ++j) {
      float av = a[kt * 8 + j] * ic;
      unsigned short u = f2bf(av);
      ahi[kt][j] = (short)u;
      alo[kt][j] = (short)f2bf(av - bf2f(u));
    }
  }

  f32x4 acc[4] = {{0.f, 0.f, 0.f, 0.f}, {0.f, 0.f, 0.f, 0.f}, {0.f, 0.f, 0.f, 0.f}, {0.f, 0.f, 0.f, 0.f}};
#pragma unroll
  for (int kt = 0; kt < 2; ++kt) {
#pragma unroll
    for (int ct = 0; ct < 4; ++ct) {
      bf16x8 lh = lwhi[(kt * 4 + ct) * 64 + lane];
      bf16x8 ll = lwlo[(kt * 4 + ct) * 64 + lane];
      bf16x8 rh = rwhi[(kt * 4 + ct) * 64 + lane];
      bf16x8 rl = rwlo[(kt * 4 + ct) * 64 + lane];
      acc[ct] = __builtin_amdgcn_mfma_f32_16x16x32_bf16(ahi[kt], lh, acc[ct], 0, 0, 0);
      acc[ct] = __builtin_amdgcn_mfma_f32_16x16x32_bf16(alo[kt], lh, acc[ct], 0, 0, 0);
      acc[ct] = __builtin_amdgcn_mfma_f32_16x16x32_bf16(ahi[kt], ll, acc[ct], 0, 0, 0);
      acc[ct] = __builtin_amdgcn_mfma_f32_16x16x32_bf16(hv[kt], rh, acc[ct], 0, 0, 0);
      acc[ct] = __builtin_amdgcn_mfma_f32_16x16x32_bf16(hv[kt], rl, acc[ct], 0, 0, 0);
    }
  }
#pragma unroll
  for (int ct = 0; ct < 4; ++ct) {
    float bb = lb[ct * 16 + er];
#pragma unroll
    for (int r = 0; r < 4; ++r) {
      float v = fmaxf(acc[ct][r] + bb, 0.f);
      size_t idx = (size_t)(R + kb * 4 + r) * HID + ct * 16 + er;
      if (hout_f32) hout_f32[idx] = v;
      hbf_out[idx] = f2bf(v);
    }
  }
}

// ---- P precompute: Ps=h@W1top, Pd=h@W1bot, stored e4m3 in [node][128B] rows
//      (C-frag-permuted layout: byte er*4+ct <-> feature ct*16+er) ----
__global__ void k_pcomp(const unsigned short* __restrict__ hbf, const bf16x8* __restrict__ w1s,
                        const bf16x8* __restrict__ w1d, unsigned int* __restrict__ pfp8) {
  const int lane = threadIdx.x & 63;
  const int er = lane & 15, kb = lane >> 4;
  const int gw = (blockIdx.x * blockDim.x + threadIdx.x) >> 6;
  if (gw >= NTILES) return;
  const int R = gw * 16;
  const int n = R + er;
  bf16x8 a0 = *reinterpret_cast<const bf16x8*>(hbf + (size_t)n * HID + kb * 8);
  bf16x8 a1 = *reinterpret_cast<const bf16x8*>(hbf + (size_t)n * HID + 32 + kb * 8);
  f32x4 as[4] = {{0.f, 0.f, 0.f, 0.f}, {0.f, 0.f, 0.f, 0.f}, {0.f, 0.f, 0.f, 0.f}, {0.f, 0.f, 0.f, 0.f}};
  f32x4 ad[4] = {{0.f, 0.f, 0.f, 0.f}, {0.f, 0.f, 0.f, 0.f}, {0.f, 0.f, 0.f, 0.f}, {0.f, 0.f, 0.f, 0.f}};
#pragma unroll
  for (int ct = 0; ct < 4; ++ct) {
    as[ct] = __builtin_amdgcn_mfma_f32_16x16x32_bf16(a0, w1s[(0 * 4 + ct) * 64 + lane], as[ct], 0, 0, 0);
    as[ct] = __builtin_amdgcn_mfma_f32_16x16x32_bf16(a1, w1s[(1 * 4 + ct) * 64 + lane], as[ct], 0, 0, 0);
    ad[ct] = __builtin_amdgcn_mfma_f32_16x16x32_bf16(a0, w1d[(0 * 4 + ct) * 64 + lane], ad[ct], 0, 0, 0);
    ad[ct] = __builtin_amdgcn_mfma_f32_16x16x32_bf16(a1, w1d[(1 * 4 + ct) * 64 + lane], ad[ct], 0, 0, 0);
  }
#pragma unroll
  for (int r = 0; r < 4; ++r) {
    int node = R + kb * 4 + r;
    unsigned int u = (unsigned)__builtin_amdgcn_cvt_pk_fp8_f32(as[0][r], as[1][r], 0, false);
    u = (unsigned)__builtin_amdgcn_cvt_pk_fp8_f32(as[2][r], as[3][r], (int)u, true);
    pfp8[(size_t)node * 32 + er] = u;
    unsigned int v = (unsigned)__builtin_amdgcn_cvt_pk_fp8_f32(ad[0][r], ad[1][r], 0, false);
    v = (unsigned)__builtin_amdgcn_cvt_pk_fp8_f32(ad[2][r], ad[3][r], (int)v, true);
    pfp8[(size_t)node * 32 + 16 + er] = v;
  }
}

// ---- edge head: VALU-only fp8 P gather (1 line per operand) + fused mean ----
__global__ void k_edge_head_p(const int* __restrict__ src, const int* __restrict__ dst,
                              const unsigned int* __restrict__ pfp8,
                              const float* __restrict__ b1, const float* __restrict__ w2,
                              const float* __restrict__ b2, float* __restrict__ scores,
                              float* __restrict__ out_mean) {
  const int lane = threadIdx.x & 63;
  const int wid = threadIdx.x >> 6;
  const int wpb = blockDim.x >> 6;
  const int nw = gridDim.x * wpb;
  const int er = lane & 15, kb = lane >> 4;
  const int ntiles = N_EDGES / 16;
  float b1v[4][4], w2v[4][4];
#pragma unroll
  for (int q = 0; q < 4; ++q)
#pragma unroll
    for (int ct = 0; ct < 4; ++ct) {
      b1v[q][ct] = b1[ct * 16 + kb * 4 + q];
      w2v[q][ct] = w2[ct * 16 + kb * 4 + q];
    }
  const float bb = b2[0];
  float msum = 0.f;
  for (int tile = blockIdx.x * wpb + wid; tile < ntiles; tile += nw) {
    int e = tile * 16 + er;
    int s = src[e], d = dst[e];
    u32x4 ap = *reinterpret_cast<const u32x4*>(pfp8 + (size_t)s * 32 + kb * 4);
    u32x4 bp = *reinterpret_cast<const u32x4*>(pfp8 + (size_t)d * 32 + 16 + kb * 4);
    float part = 0.f;
#pragma unroll
    for (int q = 0; q < 4; ++q) {
      f32x2 s01 = __builtin_amdgcn_cvt_pk_f32_fp8(ap[q], false);
      f32x2 s23 = __builtin_amdgcn_cvt_pk_f32_fp8(ap[q], true);
      f32x2 d01 = __builtin_amdgcn_cvt_pk_f32_fp8(bp[q], false);
      f32x2 d23 = __builtin_amdgcn_cvt_pk_f32_fp8(bp[q], true);
      part += fmaxf(s01[0] + d01[0] + b1v[q][0], 0.f) * w2v[q][0];
      part += fmaxf(s01[1] + d01[1] + b1v[q][1], 0.f) * w2v[q][1];
      part += fmaxf(s23[0] + d23[0] + b1v[q][2], 0.f) * w2v[q][2];
      part += fmaxf(s23[1] + d23[1] + b1v[q][3], 0.f) * w2v[q][3];
    }
    part += __shfl_xor(part, 16);
    part += __shfl_xor(part, 32);
    if (lane < 16) {
      float sc = 1.f / (1.f + __expf(-(part + bb)));
      scores[e] = sc;
      msum += sc;
    }
  }
#pragma unroll
  for (int o = 1; o < 64; o <<= 1) msum += __shfl_xor(msum, o);
  __shared__ float bs[8];
  if (lane == 0) bs[wid] = msum;
  __syncthreads();
  if (threadIdx.x == 0) {
    float t = 0.f;
    for (int i = 0; i < wpb; ++i) t += bs[i];
    atomicAdd(out_mean, t * (1.f / (float)N_EDGES));
  }
}

extern "C" void kernel_launch(void* const* d_in, const int* in_sizes, int n_in,
                              void* d_out, int out_size, void* d_ws, size_t ws_size,
                              hipStream_t stream) {
  const float* x = (const float*)d_in[0];
  const int* ei = (const int*)d_in[1];
  const int* src = ei;
  const int* dst = ei + N_EDGES;
  const float* enc_w = (const float*)d_in[3];
  const float* enc_b = (const float*)d_in[4];
  const float* conv_lw = (const float*)d_in[7];
  const float* conv_lb = (const float*)d_in[8];
  const float* conv_rw = (const float*)d_in[9];
  const float* eh_w1 = (const float*)d_in[10];
  const float* eh_b1 = (const float*)d_in[11];
  const float* eh_w2 = (const float*)d_in[12];
  const float* eh_b2 = (const float*)d_in[13];

  float* out_scores = (float*)d_out;
  float* out_mean = out_scores + N_EDGES;
  float* out_h = out_mean + 1;

  char* p = (char*)d_ws;
  unsigned int* tbuf = (unsigned int*)p;                  p += (size_t)N_EDGES * 4;
  int* csr = (int*)p;                                     p += (size_t)N_EDGES * 4;
  int* off = (int*)p;                                     p += (size_t)(N_NODES + 1) * 4;
  int* bcnt = (int*)p;                                    p += NBUCK * 4;
  int* bbase = (int*)p;                                   p += (NBUCK + 1) * 4;
  int* bcur = (int*)p;                                    p += NBUCK * 4 + 256;
  unsigned short* h0bf = (unsigned short*)p;              p += (size_t)N_NODES * HID * 2;
  unsigned short* h1bf = (unsigned short*)p;              p += (size_t)N_NODES * HID * 2;
  unsigned int* pfp8 = (unsigned int*)p;                  p += (size_t)N_NODES * 128;
  unsigned short* encwh = (unsigned short*)p;             p += 8192 * 2;
  unsigned short* encwl = (unsigned short*)p;             p += 8192 * 2;
  unsigned short* cw = (unsigned short*)p;                p += 8 * 4096 * 2;
  unsigned short* w1s = (unsigned short*)p;               p += 4096 * 2;
  unsigned short* w1d = (unsigned short*)p;               p += 4096 * 2;
  const bf16x8 *lwhi0 = (const bf16x8*)(cw + 0 * 4096), *lwlo0 = (const bf16x8*)(cw + 1 * 4096);
  const bf16x8 *rwhi0 = (const bf16x8*)(cw + 2 * 4096), *rwlo0 = (const bf16x8*)(cw + 3 * 4096);
  const bf16x8 *lwhi1 = (const bf16x8*)(cw + 4 * 4096), *lwlo1 = (const bf16x8*)(cw + 5 * 4096);
  const bf16x8 *rwhi1 = (const bf16x8*)(cw + 6 * 4096), *rwlo1 = (const bf16x8*)(cw + 7 * 4096);

  // 1. packs + zeroing
  k_pack_all<<<32, 256, 0, stream>>>(enc_w, conv_lw, conv_rw, eh_w1, encwh, encwl, cw,
                                     w1s, w1d, bcnt, out_mean);
  // 2-5. CSR build (bucketed)
  k_bhist<<<512, 256, 0, stream>>>(dst, bcnt);
  k_bscan<<<1, 64, 0, stream>>>(bcnt, bbase, bcur, off);
  k_partition<<<(N_EDGES + EPB_A - 1) / EPB_A, 256, 0, stream>>>(src, dst, bcur, tbuf);
  k_bucket2<<<NBUCK, NPB, 0, stream>>>(bbase, tbuf, csr, off);
  // 6. encoder (bf16 h only)
  k_encode_mfma<<<1024, 256, 0, stream>>>(x, (const bf16x8*)encwh, (const bf16x8*)encwl,
                                          enc_b, h0bf);
  // 7-8. fused SAGE layers (bf16-only h; layer 2 also writes f32 out_h)
  const int LGRID = (NTILES + 3) / 4;
  k_layer<<<LGRID, 256, 0, stream>>>(off, csr, h0bf, lwhi0, lwlo0, conv_lb,
                                     rwhi0, rwlo0, nullptr, h1bf);
  k_layer<<<LGRID, 256, 0, stream>>>(off, csr, h1bf, lwhi1, lwlo1, conv_lb + HID,
                                     rwhi1, rwlo1, out_h, h0bf);
  // 9. P precompute (fp8), 10. edge head + mean
  k_pcomp<<<LGRID, 256, 0, stream>>>(h0bf, (const bf16x8*)w1s, (const bf16x8*)w1d, pfp8);
  k_edge_head_p<<<2048, 256, 0, stream>>>(src, dst, pfp8, eh_b1, eh_w2, eh_b2,
                                          out_scores, out_mean);
}

// Round 6
// 318.663 us; speedup vs baseline: 4.8590x; 1.0024x over previous
//
#include <hip/hip_runtime.h>
#include <hip/hip_bf16.h>

#define N_NODES 100000
#define N_EDGES 1600000
#define HID 64
#define NODE_DIM 128
#define NPB 512                              // nodes per bucket (dst>>9)
#define NBUCK ((N_NODES + NPB - 1) / NPB)    // 196
#define EPB_A 4096                           // edges per partition block
#define NTILES (N_NODES / 16)                // 6250

typedef __attribute__((ext_vector_type(8))) short bf16x8;
typedef __attribute__((ext_vector_type(8))) float f32x8;
typedef __attribute__((ext_vector_type(4))) float f32x4;
typedef __attribute__((ext_vector_type(2))) float f32x2;
typedef __attribute__((ext_vector_type(4))) unsigned int u32x4;

__device__ __forceinline__ unsigned short f2bf(float f) {
  __hip_bfloat16 h = __float2bfloat16(f);
  return *reinterpret_cast<unsigned short*>(&h);
}
__device__ __forceinline__ float bf2f(unsigned short u) {
  __hip_bfloat16 h = *reinterpret_cast<__hip_bfloat16*>(&u);
  return __bfloat162float(h);
}

// pack one element of W[K][64] into MFMA B-frag order, hi/lo bf16 split
__device__ __forceinline__ void pack_one(const float* __restrict__ w,
                                         unsigned short* __restrict__ whi,
                                         unsigned short* __restrict__ wlo, int i) {
  int j = i & 7, lane = (i >> 3) & 63, ct = (i >> 9) & 3, kt = i >> 11;
  int k = kt * 32 + (lane >> 4) * 8 + j;
  int c = ct * 16 + (lane & 15);
  float v = w[k * HID + c];
  unsigned short hi = f2bf(v);
  whi[i] = hi;
  wlo[i] = f2bf(v - bf2f(hi));
}
__device__ __forceinline__ void pack_one_hi(const float* __restrict__ w,
                                            unsigned short* __restrict__ whi, int i) {
  int j = i & 7, lane = (i >> 3) & 63, ct = (i >> 9) & 3, kt = i >> 11;
  int k = kt * 32 + (lane >> 4) * 8 + j;
  int c = ct * 16 + (lane & 15);
  whi[i] = f2bf(w[k * HID + c]);
}

// ---- all weight packing + per-call zeroing, one launch (grid 32x256) ----
__global__ void k_pack_all(const float* __restrict__ enc_w, const float* __restrict__ conv_lw,
                           const float* __restrict__ conv_rw, const float* __restrict__ eh_w1,
                           unsigned short* __restrict__ encwh, unsigned short* __restrict__ encwl,
                           unsigned short* __restrict__ cw, unsigned short* __restrict__ w1s,
                           unsigned short* __restrict__ w1d, int* __restrict__ bcnt,
                           float* __restrict__ out_mean) {
  int i = blockIdx.x * blockDim.x + threadIdx.x;
  if (i < NODE_DIM * HID) pack_one(enc_w, encwh, encwl, i);
  if (i < HID * HID) {
    pack_one(conv_lw, cw + 0 * 4096, cw + 1 * 4096, i);
    pack_one(conv_rw, cw + 2 * 4096, cw + 3 * 4096, i);
    pack_one(conv_lw + HID * HID, cw + 4 * 4096, cw + 5 * 4096, i);
    pack_one(conv_rw + HID * HID, cw + 6 * 4096, cw + 7 * 4096, i);
  }
  if (i < HID * HID) {
    pack_one_hi(eh_w1, w1s, i);                  // W1[0:64][:]
    pack_one_hi(eh_w1 + HID * HID, w1d, i);      // W1[64:128][:]
  }
  if (i < NBUCK) bcnt[i] = 0;
  if (i == 0) *out_mean = 0.f;
}

// ---- bucket-level histogram (196 counters) ----
__global__ void k_bhist(const int* __restrict__ dst, int* __restrict__ bcnt) {
  __shared__ int h[NBUCK];
  for (int i = threadIdx.x; i < NBUCK; i += blockDim.x) h[i] = 0;
  __syncthreads();
  int stride = gridDim.x * blockDim.x;
  for (int e = blockIdx.x * blockDim.x + threadIdx.x; e < N_EDGES; e += stride)
    atomicAdd(&h[dst[e] >> 9], 1);
  __syncthreads();
  for (int i = threadIdx.x; i < NBUCK; i += blockDim.x)
    if (h[i]) atomicAdd(&bcnt[i], h[i]);
}

// ---- tiny serial scan of 196 bucket counts ----
__global__ void k_bscan(const int* __restrict__ bcnt, int* __restrict__ bbase,
                        int* __restrict__ bcur, int* __restrict__ off) {
  if (threadIdx.x == 0 && blockIdx.x == 0) {
    int run = 0;
    for (int b = 0; b < NBUCK; ++b) {
      bbase[b] = run;
      bcur[b] = run;
      run += bcnt[b];
    }
    bbase[NBUCK] = run;
    off[N_NODES] = run;  // == N_EDGES
  }
}

// ---- phase A: partition edges into dst-buckets; 4B entries (src|dl<<17) ----
__global__ void k_partition(const int* __restrict__ src, const int* __restrict__ dst,
                            int* __restrict__ bcur, unsigned int* __restrict__ tbuf) {
  __shared__ int hist[NBUCK];
  for (int i = threadIdx.x; i < NBUCK; i += blockDim.x) hist[i] = 0;
  __syncthreads();
  int e0 = blockIdx.x * EPB_A;
#pragma unroll
  for (int k = 0; k < EPB_A / 256; ++k) {
    int e = e0 + k * 256 + threadIdx.x;
    if (e < N_EDGES) atomicAdd(&hist[dst[e] >> 9], 1);
  }
  __syncthreads();
  for (int b = threadIdx.x; b < NBUCK; b += blockDim.x) {
    int c = hist[b];
    hist[b] = c ? atomicAdd(&bcur[b], c) : 0;
  }
  __syncthreads();
#pragma unroll
  for (int k = 0; k < EPB_A / 256; ++k) {
    int e = e0 + k * 256 + threadIdx.x;
    if (e < N_EDGES) {
      int s = src[e], d = dst[e];
      int pos = atomicAdd(&hist[d >> 9], 1);
      tbuf[pos] = (unsigned)s | ((unsigned)(d & (NPB - 1)) << 17);
    }
  }
}

// ---- phase B: per-bucket node offsets (LDS hist+scan) + CSR rank fill ----
__global__ void k_bucket2(const int* __restrict__ bbase, const unsigned int* __restrict__ tbuf,
                          int* __restrict__ csr, int* __restrict__ off) {
  __shared__ int cnt[NPB];
  __shared__ int wsum[8];
  const int b = blockIdx.x;
  const int n0 = b * NPB;
  const int nn = min(NPB, N_NODES - n0);
  const int t0 = bbase[b], t1 = bbase[b + 1];
  cnt[threadIdx.x] = 0;  // blockDim == NPB == 512
  __syncthreads();
  for (int t = t0 + threadIdx.x; t < t1; t += blockDim.x)
    atomicAdd(&cnt[tbuf[t] >> 17], 1);
  __syncthreads();
  int v = (threadIdx.x < nn) ? cnt[threadIdx.x] : 0;
  int lane = threadIdx.x & 63, wid = threadIdx.x >> 6;
  int s = v;
#pragma unroll
  for (int d = 1; d < 64; d <<= 1) {
    int t = __shfl_up(s, d);
    if (lane >= d) s += t;
  }
  if (lane == 63) wsum[wid] = s;
  __syncthreads();
  if (wid == 0 && lane < 8) {
    int t = wsum[lane];
#pragma unroll
    for (int d = 1; d < 8; d <<= 1) {
      int u = __shfl_up(t, d);
      if (lane >= d) t += u;
    }
    wsum[lane] = t;
  }
  __syncthreads();
  int cur0 = t0 + (s - v) + (wid > 0 ? wsum[wid - 1] : 0);
  __syncthreads();
  if (threadIdx.x < nn) {
    off[n0 + threadIdx.x] = cur0;
    cnt[threadIdx.x] = cur0;
  }
  __syncthreads();
  for (int t = t0 + threadIdx.x; t < t1; t += blockDim.x) {
    unsigned int u = tbuf[t];
    int pos = atomicAdd(&cnt[u >> 17], 1);
    csr[pos] = (int)(u & 0x1FFFFu);
  }
}

// ---- encoder: h = relu(x @ W + b) via MFMA; writes bf16 h only ----
__global__ void k_encode_mfma(const float* __restrict__ x, const bf16x8* __restrict__ whi,
                              const bf16x8* __restrict__ wlo, const float* __restrict__ b,
                              unsigned short* __restrict__ hbf) {
  const int lane = threadIdx.x & 63;
  const int er = lane & 15, kb = lane >> 4;
  int gw = (blockIdx.x * blockDim.x + threadIdx.x) >> 6;
  int nw = (gridDim.x * blockDim.x) >> 6;
  for (int tile = gw; tile < NTILES; tile += nw) {
    int R = tile * 16;
    f32x4 acc[4] = {{0.f, 0.f, 0.f, 0.f}, {0.f, 0.f, 0.f, 0.f}, {0.f, 0.f, 0.f, 0.f}, {0.f, 0.f, 0.f, 0.f}};
#pragma unroll
    for (int kt = 0; kt < 4; ++kt) {
      f32x8 xv = *reinterpret_cast<const f32x8*>(x + (size_t)(R + er) * NODE_DIM + kt * 32 + kb * 8);
      bf16x8 ahi, alo;
#pragma unroll
      for (int j = 0; j < 8; ++j) {
        unsigned short hi = f2bf(xv[j]);
        ahi[j] = (short)hi;
        alo[j] = (short)f2bf(xv[j] - bf2f(hi));
      }
#pragma unroll
      for (int ct = 0; ct < 4; ++ct) {
        bf16x8 bh = whi[(kt * 4 + ct) * 64 + lane];
        bf16x8 bl = wlo[(kt * 4 + ct) * 64 + lane];
        acc[ct] = __builtin_amdgcn_mfma_f32_16x16x32_bf16(ahi, bh, acc[ct], 0, 0, 0);
        acc[ct] = __builtin_amdgcn_mfma_f32_16x16x32_bf16(alo, bh, acc[ct], 0, 0, 0);
        acc[ct] = __builtin_amdgcn_mfma_f32_16x16x32_bf16(ahi, bl, acc[ct], 0, 0, 0);
      }
    }
#pragma unroll
    for (int ct = 0; ct < 4; ++ct) {
      float bb = b[ct * 16 + er];
#pragma unroll
      for (int r = 0; r < 4; ++r)
        hbf[(size_t)(R + kb * 4 + r) * HID + ct * 16 + er] = f2bf(fmaxf(acc[ct][r] + bb, 0.f));
    }
  }
}

// ---- fused SAGE layer, bf16-only h: register mean-agg + MFMA update ----
__global__ void k_layer(const int* __restrict__ off, const int* __restrict__ csr,
                        const unsigned short* __restrict__ hbf_in,
                        const bf16x8* __restrict__ lwhi, const bf16x8* __restrict__ lwlo,
                        const float* __restrict__ lb,
                        const bf16x8* __restrict__ rwhi, const bf16x8* __restrict__ rwlo,
                        float* __restrict__ hout_f32, unsigned short* __restrict__ hbf_out) {
  const int lane = threadIdx.x & 63;
  const int er = lane & 15, kb = lane >> 4;
  const int gw = (blockIdx.x * blockDim.x + threadIdx.x) >> 6;
  if (gw >= NTILES) return;
  const int R = gw * 16;
  const int n = R + er;
  const int s0 = off[n], s1 = off[n + 1];

  float a[16];
#pragma unroll
  for (int j = 0; j < 16; ++j) a[j] = 0.f;
  int it = s0;
  for (; it + 2 <= s1; it += 2) {
    int i0 = csr[it], i1 = csr[it + 1];
    bf16x8 u0 = *reinterpret_cast<const bf16x8*>(hbf_in + (size_t)i0 * HID + kb * 8);
    bf16x8 u1 = *reinterpret_cast<const bf16x8*>(hbf_in + (size_t)i0 * HID + 32 + kb * 8);
    bf16x8 v0 = *reinterpret_cast<const bf16x8*>(hbf_in + (size_t)i1 * HID + kb * 8);
    bf16x8 v1 = *reinterpret_cast<const bf16x8*>(hbf_in + (size_t)i1 * HID + 32 + kb * 8);
#pragma unroll
    for (int j = 0; j < 8; ++j) {
      a[j] += bf2f((unsigned short)u0[j]) + bf2f((unsigned short)v0[j]);
      a[8 + j] += bf2f((unsigned short)u1[j]) + bf2f((unsigned short)v1[j]);
    }
  }
  if (it < s1) {
    int i0 = csr[it];
    bf16x8 u0 = *reinterpret_cast<const bf16x8*>(hbf_in + (size_t)i0 * HID + kb * 8);
    bf16x8 u1 = *reinterpret_cast<const bf16x8*>(hbf_in + (size_t)i0 * HID + 32 + kb * 8);
#pragma unroll
    for (int j = 0; j < 8; ++j) {
      a[j] += bf2f((unsigned short)u0[j]);
      a[8 + j] += bf2f((unsigned short)u1[j]);
    }
  }
  const float ic = (s1 > s0) ? 1.f / (float)(s1 - s0) : 0.f;

  // self A-frags (bf16 h directly) + agg hi/lo split
  bf16x8 hv[2], ahi[2], alo[2];
  hv[0] = *reinterpret_cast<const bf16x8*>(hbf_in + (size_t)n * HID + kb * 8);
  hv[1] = *reinterpret_cast<const bf16x8*>(hbf_in + (size_t)n * HID + 32 + kb * 8);
#pragma unroll
  for (int kt = 0; kt < 2; ++kt) {
#pragma unroll
    for (int j = 0; j < 8; ++j) {
      float av = a[kt * 8 + j] * ic;
      unsigned short u = f2bf(av);
      ahi[kt][j] = (short)u;
      alo[kt][j] = (short)f2bf(av - bf2f(u));
    }
  }

  f32x4 acc[4] = {{0.f, 0.f, 0.f, 0.f}, {0.f, 0.f, 0.f, 0.f}, {0.f, 0.f, 0.f, 0.f}, {0.f, 0.f, 0.f, 0.f}};
#pragma unroll
  for (int kt = 0; kt < 2; ++kt) {
#pragma unroll
    for (int ct = 0; ct < 4; ++ct) {
      bf16x8 lh = lwhi[(kt * 4 + ct) * 64 + lane];
      bf16x8 ll = lwlo[(kt * 4 + ct) * 64 + lane];
      bf16x8 rh = rwhi[(kt * 4 + ct) * 64 + lane];
      bf16x8 rl = rwlo[(kt * 4 + ct) * 64 + lane];
      acc[ct] = __builtin_amdgcn_mfma_f32_16x16x32_bf16(ahi[kt], lh, acc[ct], 0, 0, 0);
      acc[ct] = __builtin_amdgcn_mfma_f32_16x16x32_bf16(alo[kt], lh, acc[ct], 0, 0, 0);
      acc[ct] = __builtin_amdgcn_mfma_f32_16x16x32_bf16(ahi[kt], ll, acc[ct], 0, 0, 0);
      acc[ct] = __builtin_amdgcn_mfma_f32_16x16x32_bf16(hv[kt], rh, acc[ct], 0, 0, 0);
      acc[ct] = __builtin_amdgcn_mfma_f32_16x16x32_bf16(hv[kt], rl, acc[ct], 0, 0, 0);
    }
  }
#pragma unroll
  for (int ct = 0; ct < 4; ++ct) {
    float bb = lb[ct * 16 + er];
#pragma unroll
    for (int r = 0; r < 4; ++r) {
      float v = fmaxf(acc[ct][r] + bb, 0.f);
      size_t idx = (size_t)(R + kb * 4 + r) * HID + ct * 16 + er;
      if (hout_f32) hout_f32[idx] = v;
      hbf_out[idx] = f2bf(v);
    }
  }
}

// ---- P precompute: Ps=h@W1top, Pd=h@W1bot, stored e4m3 in [node][128B] rows
//      (C-frag-permuted layout: byte er*4+ct <-> feature ct*16+er) ----
__global__ void k_pcomp(const unsigned short* __restrict__ hbf, const bf16x8* __restrict__ w1s,
                        const bf16x8* __restrict__ w1d, unsigned int* __restrict__ pfp8) {
  const int lane = threadIdx.x & 63;
  const int er = lane & 15, kb = lane >> 4;
  const int gw = (blockIdx.x * blockDim.x + threadIdx.x) >> 6;
  if (gw >= NTILES) return;
  const int R = gw * 16;
  const int n = R + er;
  bf16x8 a0 = *reinterpret_cast<const bf16x8*>(hbf + (size_t)n * HID + kb * 8);
  bf16x8 a1 = *reinterpret_cast<const bf16x8*>(hbf + (size_t)n * HID + 32 + kb * 8);
  f32x4 as[4] = {{0.f, 0.f, 0.f, 0.f}, {0.f, 0.f, 0.f, 0.f}, {0.f, 0.f, 0.f, 0.f}, {0.f, 0.f, 0.f, 0.f}};
  f32x4 ad[4] = {{0.f, 0.f, 0.f, 0.f}, {0.f, 0.f, 0.f, 0.f}, {0.f, 0.f, 0.f, 0.f}, {0.f, 0.f, 0.f, 0.f}};
#pragma unroll
  for (int ct = 0; ct < 4; ++ct) {
    as[ct] = __builtin_amdgcn_mfma_f32_16x16x32_bf16(a0, w1s[(0 * 4 + ct) * 64 + lane], as[ct], 0, 0, 0);
    as[ct] = __builtin_amdgcn_mfma_f32_16x16x32_bf16(a1, w1s[(1 * 4 + ct) * 64 + lane], as[ct], 0, 0, 0);
    ad[ct] = __builtin_amdgcn_mfma_f32_16x16x32_bf16(a0, w1d[(0 * 4 + ct) * 64 + lane], ad[ct], 0, 0, 0);
    ad[ct] = __builtin_amdgcn_mfma_f32_16x16x32_bf16(a1, w1d[(1 * 4 + ct) * 64 + lane], ad[ct], 0, 0, 0);
  }
#pragma unroll
  for (int r = 0; r < 4; ++r) {
    int node = R + kb * 4 + r;
    unsigned int u = (unsigned)__builtin_amdgcn_cvt_pk_fp8_f32(as[0][r], as[1][r], 0, false);
    u = (unsigned)__builtin_amdgcn_cvt_pk_fp8_f32(as[2][r], as[3][r], (int)u, true);
    pfp8[(size_t)node * 32 + er] = u;
    unsigned int v = (unsigned)__builtin_amdgcn_cvt_pk_fp8_f32(ad[0][r], ad[1][r], 0, false);
    v = (unsigned)__builtin_amdgcn_cvt_pk_fp8_f32(ad[2][r], ad[3][r], (int)v, true);
    pfp8[(size_t)node * 32 + 16 + er] = v;
  }
}

// ---- edge head: VALU-only fp8 P gather (1 line per operand) + fused mean ----
__global__ void k_edge_head_p(const int* __restrict__ src, const int* __restrict__ dst,
                              const unsigned int* __restrict__ pfp8,
                              const float* __restrict__ b1, const float* __restrict__ w2,
                              const float* __restrict__ b2, float* __restrict__ scores,
                              float* __restrict__ out_mean) {
  const int lane = threadIdx.x & 63;
  const int wid = threadIdx.x >> 6;
  const int wpb = blockDim.x >> 6;
  const int nw = gridDim.x * wpb;
  const int er = lane & 15, kb = lane >> 4;
  const int ntiles = N_EDGES / 16;
  float b1v[4][4], w2v[4][4];
#pragma unroll
  for (int q = 0; q < 4; ++q)
#pragma unroll
    for (int ct = 0; ct < 4; ++ct) {
      b1v[q][ct] = b1[ct * 16 + kb * 4 + q];
      w2v[q][ct] = w2[ct * 16 + kb * 4 + q];
    }
  const float bb = b2[0];
  float msum = 0.f;
  for (int tile = blockIdx.x * wpb + wid; tile < ntiles; tile += nw) {
    int e = tile * 16 + er;
    int s = src[e], d = dst[e];
    u32x4 ap = *reinterpret_cast<const u32x4*>(pfp8 + (size_t)s * 32 + kb * 4);
    u32x4 bp = *reinterpret_cast<const u32x4*>(pfp8 + (size_t)d * 32 + 16 + kb * 4);
    float part = 0.f;
#pragma unroll
    for (int q = 0; q < 4; ++q) {
      f32x2 s01 = __builtin_amdgcn_cvt_pk_f32_fp8(ap[q], false);
      f32x2 s23 = __builtin_amdgcn_cvt_pk_f32_fp8(ap[q], true);
      f32x2 d01 = __builtin_amdgcn_cvt_pk_f32_fp8(bp[q], false);
      f32x2 d23 = __builtin_amdgcn_cvt_pk_f32_fp8(bp[q], true);
      part += fmaxf(s01[0] + d01[0] + b1v[q][0], 0.f) * w2v[q][0];
      part += fmaxf(s01[1] + d01[1] + b1v[q][1], 0.f) * w2v[q][1];
      part += fmaxf(s23[0] + d23[0] + b1v[q][2], 0.f) * w2v[q][2];
      part += fmaxf(s23[1] + d23[1] + b1v[q][3], 0.f) * w2v[q][3];
    }
    part += __shfl_xor(part, 16);
    part += __shfl_xor(part, 32);
    if (lane < 16) {
      float sc = 1.f / (1.f + __expf(-(part + bb)));
      scores[e] = sc;
      msum += sc;
    }
  }
#pragma unroll
  for (int o = 1; o < 64; o <<= 1) msum += __shfl_xor(msum, o);
  __shared__ float bs[8];
  if (lane == 0) bs[wid] = msum;
  __syncthreads();
  if (threadIdx.x == 0) {
    float t = 0.f;
    for (int i = 0; i < wpb; ++i) t += bs[i];
    atomicAdd(out_mean, t * (1.f / (float)N_EDGES));
  }
}

extern "C" void kernel_launch(void* const* d_in, const int* in_sizes, int n_in,
                              void* d_out, int out_size, void* d_ws, size_t ws_size,
                              hipStream_t stream) {
  const float* x = (const float*)d_in[0];
  const int* ei = (const int*)d_in[1];
  const int* src = ei;
  const int* dst = ei + N_EDGES;
  const float* enc_w = (const float*)d_in[3];
  const float* enc_b = (const float*)d_in[4];
  const float* conv_lw = (const float*)d_in[7];
  const float* conv_lb = (const float*)d_in[8];
  const float* conv_rw = (const float*)d_in[9];
  const float* eh_w1 = (const float*)d_in[10];
  const float* eh_b1 = (const float*)d_in[11];
  const float* eh_w2 = (const float*)d_in[12];
  const float* eh_b2 = (const float*)d_in[13];

  float* out_scores = (float*)d_out;
  float* out_mean = out_scores + N_EDGES;
  float* out_h = out_mean + 1;

  char* p = (char*)d_ws;
  unsigned int* tbuf = (unsigned int*)p;                  p += (size_t)N_EDGES * 4;
  int* csr = (int*)p;                                     p += (size_t)N_EDGES * 4;
  int* off = (int*)p;                                     p += (size_t)(N_NODES + 1) * 4;
  int* bcnt = (int*)p;                                    p += NBUCK * 4;
  int* bbase = (int*)p;                                   p += (NBUCK + 1) * 4;
  int* bcur = (int*)p;                                    p += NBUCK * 4 + 256;
  unsigned short* h0bf = (unsigned short*)p;              p += (size_t)N_NODES * HID * 2;
  unsigned short* h1bf = (unsigned short*)p;              p += (size_t)N_NODES * HID * 2;
  unsigned int* pfp8 = (unsigned int*)p;                  p += (size_t)N_NODES * 128;
  unsigned short* encwh = (unsigned short*)p;             p += 8192 * 2;
  unsigned short* encwl = (unsigned short*)p;             p += 8192 * 2;
  unsigned short* cw = (unsigned short*)p;                p += 8 * 4096 * 2;
  unsigned short* w1s = (unsigned short*)p;               p += 4096 * 2;
  unsigned short* w1d = (unsigned short*)p;               p += 4096 * 2;
  const bf16x8 *lwhi0 = (const bf16x8*)(cw + 0 * 4096), *lwlo0 = (const bf16x8*)(cw + 1 * 4096);
  const bf16x8 *rwhi0 = (const bf16x8*)(cw + 2 * 4096), *rwlo0 = (const bf16x8*)(cw + 3 * 4096);
  const bf16x8 *lwhi1 = (const bf16x8*)(cw + 4 * 4096), *lwlo1 = (const bf16x8*)(cw + 5 * 4096);
  const bf16x8 *rwhi1 = (const bf16x8*)(cw + 6 * 4096), *rwlo1 = (const bf16x8*)(cw + 7 * 4096);

  // 1. packs + zeroing
  k_pack_all<<<32, 256, 0, stream>>>(enc_w, conv_lw, conv_rw, eh_w1, encwh, encwl, cw,
                                     w1s, w1d, bcnt, out_mean);
  // 2-5. CSR build (bucketed)
  k_bhist<<<512, 256, 0, stream>>>(dst, bcnt);
  k_bscan<<<1, 64, 0, stream>>>(bcnt, bbase, bcur, off);
  k_partition<<<(N_EDGES + EPB_A - 1) / EPB_A, 256, 0, stream>>>(src, dst, bcur, tbuf);
  k_bucket2<<<NBUCK, NPB, 0, stream>>>(bbase, tbuf, csr, off);
  // 6. encoder (bf16 h only)
  k_encode_mfma<<<1024, 256, 0, stream>>>(x, (const bf16x8*)encwh, (const bf16x8*)encwl,
                                          enc_b, h0bf);
  // 7-8. fused SAGE layers (bf16-only h; layer 2 also writes f32 out_h)
  const int LGRID = (NTILES + 3) / 4;
  k_layer<<<LGRID, 256, 0, stream>>>(off, csr, h0bf, lwhi0, lwlo0, conv_lb,
                                     rwhi0, rwlo0, nullptr, h1bf);
  k_layer<<<LGRID, 256, 0, stream>>>(off, csr, h1bf, lwhi1, lwlo1, conv_lb + HID,
                                     rwhi1, rwlo1, out_h, h0bf);
  // 9. P precompute (fp8), 10. edge head + mean
  k_pcomp<<<LGRID, 256, 0, stream>>>(h0bf, (const bf16x8*)w1s, (const bf16x8*)w1d, pfp8);
  k_edge_head_p<<<2048, 256, 0, stream>>>(src, dst, pfp8, eh_b1, eh_w2, eh_b2,
                                          out_scores, out_mean);
}